// Round 1
// baseline (1621.002 us; speedup 1.0000x reference)
//
#include <hip/hip_runtime.h>
#include <math.h>

#define BM 64
#define BN 64
#define BK 16

// C[m,n] = sum_k A[m,k]*B[n,k]  (A:[M,K] row-major, B:[N,K] row-major)
// Rows n >= nsplit come from B1 (head concat of cluster_weight). M % 64 == 0, K % 16 == 0.
// DO_EXP: add bias, exp, row-sum, atomicAdd into S[m]. else: store C[m,n].
template<bool DO_EXP>
__global__ void gemm_nt(const float* __restrict__ A,
                        const float* __restrict__ B0,
                        const float* __restrict__ B1, int nsplit,
                        const float* __restrict__ bias0,
                        const float* __restrict__ bias1,
                        float* __restrict__ C,
                        float* __restrict__ S,
                        int M, int N, int K)
{
    __shared__ float As[BK][BM + 4];
    __shared__ float Bs[BK][BN + 4];

    const int tid = threadIdx.x;            // 256 threads
    const int m0 = blockIdx.x * BM;
    const int n0 = blockIdx.y * BN;
    const int tx = tid & 15;                // n direction
    const int ty = tid >> 4;                // m direction
    const int lr = tid >> 2;                // loader row 0..63
    const int lc = (tid & 3) * 4;           // loader col 0,4,8,12

    float acc[4][4] = {};

    for (int k0 = 0; k0 < K; k0 += BK) {
        // ---- load A tile (transpose into LDS) ----
        {
            const float4 v = *(const float4*)(A + (size_t)(m0 + lr) * K + k0 + lc);
            As[lc + 0][lr] = v.x; As[lc + 1][lr] = v.y;
            As[lc + 2][lr] = v.z; As[lc + 3][lr] = v.w;
        }
        // ---- load B tile (guarded, two-source) ----
        {
            const int n = n0 + lr;
            float4 v = make_float4(0.f, 0.f, 0.f, 0.f);
            if (n < N) {
                const float* src = (B1 == nullptr || n < nsplit)
                                 ? (B0 + (size_t)n * K)
                                 : (B1 + (size_t)(n - nsplit) * K);
                v = *(const float4*)(src + k0 + lc);
            }
            Bs[lc + 0][lr] = v.x; Bs[lc + 1][lr] = v.y;
            Bs[lc + 2][lr] = v.z; Bs[lc + 3][lr] = v.w;
        }
        __syncthreads();

#pragma unroll
        for (int kk = 0; kk < BK; ++kk) {
            float a[4], b[4];
            *(float4*)a = *(const float4*)&As[kk][ty * 4];
            *(float4*)b = *(const float4*)&Bs[kk][tx * 4];
#pragma unroll
            for (int i = 0; i < 4; ++i)
#pragma unroll
                for (int j = 0; j < 4; ++j)
                    acc[i][j] += a[i] * b[j];
        }
        __syncthreads();
    }

    if (DO_EXP) {
        float rowsum[4] = {0.f, 0.f, 0.f, 0.f};
#pragma unroll
        for (int i = 0; i < 4; ++i) {
#pragma unroll
            for (int j = 0; j < 4; ++j) {
                const int n = n0 + tx * 4 + j;
                if (n < N) {
                    const float bb = (B1 == nullptr || n < nsplit) ? bias0[n]
                                                                   : bias1[n - nsplit];
                    rowsum[i] += __expf(acc[i][j] + bb);
                }
            }
        }
        // reduce across the 16 tx lanes (they are contiguous within a wave)
#pragma unroll
        for (int off = 1; off < 16; off <<= 1) {
#pragma unroll
            for (int i = 0; i < 4; ++i)
                rowsum[i] += __shfl_xor(rowsum[i], off, 64);
        }
        if (tx == 0) {
#pragma unroll
            for (int i = 0; i < 4; ++i)
                atomicAdd(&S[m0 + ty * 4 + i], rowsum[i]);
        }
    } else {
#pragma unroll
        for (int i = 0; i < 4; ++i) {
#pragma unroll
            for (int j = 0; j < 4; ++j) {
                const int n = n0 + tx * 4 + j;
                if (n < N)
                    C[(size_t)(m0 + ty * 4 + i) * N + n] = acc[i][j];
            }
        }
    }
}

__global__ void zero_kernel(float* p, int n)
{
    int i = blockIdx.x * blockDim.x + threadIdx.x;
    if (i < n) p[i] = 0.f;
}

// one wave per token: compute head target/cluster logit + tail target logit
__global__ void extract_kernel(const float* __restrict__ Y0, const float* __restrict__ Y1,
                               const float* __restrict__ Y2, const float* __restrict__ Y3,
                               const int* __restrict__ target,
                               const float* __restrict__ W0, const float* __restrict__ b0,
                               const float* __restrict__ W1, const float* __restrict__ b1,
                               const float* __restrict__ W2, const float* __restrict__ b2,
                               const float* __restrict__ W3, const float* __restrict__ b3,
                               const float* __restrict__ cw, const float* __restrict__ cb,
                               float* __restrict__ headlogit, float* __restrict__ taillogit)
{
    const int token = blockIdx.x * 4 + (threadIdx.x >> 6);
    const int lane = threadIdx.x & 63;
    const int tgt = target[token];
    const int ci = (tgt < 20000) ? 0 : (tgt < 40000) ? 1 : (tgt < 200000) ? 2 : 3;

    // head logit at index (ci==0 ? tgt : 20000+ci-1)
    {
        const int h = (ci == 0) ? tgt : (20000 + ci - 1);
        const float* row;
        float bb;
        if (h < 20000) { row = W0 + (size_t)h * 1024; bb = b0[h]; }
        else           { row = cw + (size_t)(h - 20000) * 1024; bb = cb[h - 20000]; }
        const float* y = Y0 + (size_t)token * 1024;
        float s = 0.f;
        for (int k = lane; k < 1024; k += 64) s += y[k] * row[k];
#pragma unroll
        for (int off = 1; off < 64; off <<= 1) s += __shfl_xor(s, off, 64);
        if (lane == 0) headlogit[token] = s + bb;
    }

    float tl = 0.f;
    if (ci > 0) {
        const float* Y; const float* W; const float* b; int K; int l;
        if (ci == 1)      { Y = Y1; W = W1; b = b1; K = 256; l = 20000; }
        else if (ci == 2) { Y = Y2; W = W2; b = b2; K = 64;  l = 40000; }
        else              { Y = Y3; W = W3; b = b3; K = 16;  l = 200000; }
        const int r = tgt - l;
        const float* y = Y + (size_t)token * K;
        const float* row = W + (size_t)r * K;
        float s = 0.f;
        for (int k = lane; k < K; k += 64) s += y[k] * row[k];
#pragma unroll
        for (int off = 1; off < 64; off <<= 1) s += __shfl_xor(s, off, 64);
        tl = s + b[r];
    }
    if (lane == 0) taillogit[token] = tl;
}

__global__ void finalize_kernel(const float* __restrict__ S0, const float* __restrict__ S1,
                                const float* __restrict__ S2, const float* __restrict__ S3,
                                const int* __restrict__ target,
                                const float* __restrict__ headlogit,
                                const float* __restrict__ taillogit,
                                float* __restrict__ out)
{
    __shared__ float red[256];
    const int tid = threadIdx.x;
    float acc = 0.f;
    for (int token = tid; token < 1024; token += 256) {
        const int tgt = target[token];
        const int ci = (tgt < 20000) ? 0 : (tgt < 40000) ? 1 : (tgt < 200000) ? 2 : 3;
        float lp = headlogit[token] - logf(S0[token]);
        if (ci > 0) {
            const float* S = (ci == 1) ? S1 : (ci == 2) ? S2 : S3;
            lp += taillogit[token] - logf(S[token]);
        }
        acc -= lp;
    }
    red[tid] = acc;
    __syncthreads();
    for (int s = 128; s > 0; s >>= 1) {
        if (tid < s) red[tid] += red[tid + s];
        __syncthreads();
    }
    if (tid == 0) out[0] = red[0] * (1.0f / 1024.0f);
}

extern "C" void kernel_launch(void* const* d_in, const int* in_sizes, int n_in,
                              void* d_out, int out_size, void* d_ws, size_t ws_size,
                              hipStream_t stream)
{
    const float* hidden = (const float*)d_in[0];   // [1024, 1024]
    const int*   target = (const int*)d_in[1];     // [1024]
    const float* W0 = (const float*)d_in[2];  const float* b0 = (const float*)d_in[3];  const float* P0 = (const float*)d_in[4];
    const float* W1 = (const float*)d_in[5];  const float* b1 = (const float*)d_in[6];  const float* P1 = (const float*)d_in[7];
    const float* W2 = (const float*)d_in[8];  const float* b2 = (const float*)d_in[9];  const float* P2 = (const float*)d_in[10];
    const float* W3 = (const float*)d_in[11]; const float* b3 = (const float*)d_in[12]; const float* P3 = (const float*)d_in[13];
    const float* cw = (const float*)d_in[14]; const float* cb = (const float*)d_in[15];
    float* out = (float*)d_out;

    const int M = 1024;  // T*B tokens

    // workspace layout (floats)
    float* ws = (float*)d_ws;
    float* Y0 = ws;                       // 1024*1024
    float* Y1 = Y0 + 1024 * 1024;         // 1024*256
    float* Y2 = Y1 + 1024 * 256;          // 1024*64
    float* Y3 = Y2 + 1024 * 64;           // 1024*16
    float* S0 = Y3 + 1024 * 16;           // 1024
    float* S1 = S0 + 1024;
    float* S2 = S1 + 1024;
    float* S3 = S2 + 1024;
    float* headlogit = S3 + 1024;         // 1024
    float* taillogit = headlogit + 1024;  // 1024

    // zero the 4 S arrays (contiguous 4096 floats)
    zero_kernel<<<16, 256, 0, stream>>>(S0, 4096);

    // projections: Y_i = hidden @ P_i^T
    gemm_nt<false><<<dim3(M / BM, (1024 + BN - 1) / BN), 256, 0, stream>>>(
        hidden, P0, nullptr, 0, nullptr, nullptr, Y0, nullptr, M, 1024, 1024);
    gemm_nt<false><<<dim3(M / BM, (256 + BN - 1) / BN), 256, 0, stream>>>(
        hidden, P1, nullptr, 0, nullptr, nullptr, Y1, nullptr, M, 256, 1024);
    gemm_nt<false><<<dim3(M / BM, (64 + BN - 1) / BN), 256, 0, stream>>>(
        hidden, P2, nullptr, 0, nullptr, nullptr, Y2, nullptr, M, 64, 1024);
    gemm_nt<false><<<dim3(M / BM, (16 + BN - 1) / BN), 256, 0, stream>>>(
        hidden, P3, nullptr, 0, nullptr, nullptr, Y3, nullptr, M, 16, 1024);

    // exp-sums
    gemm_nt<true><<<dim3(M / BM, (20003 + BN - 1) / BN), 256, 0, stream>>>(
        Y0, W0, cw, 20000, b0, cb, nullptr, S0, M, 20003, 1024);
    gemm_nt<true><<<dim3(M / BM, (20000 + BN - 1) / BN), 256, 0, stream>>>(
        Y1, W1, nullptr, 0, b1, nullptr, nullptr, S1, M, 20000, 256);
    gemm_nt<true><<<dim3(M / BM, (160000 + BN - 1) / BN), 256, 0, stream>>>(
        Y2, W2, nullptr, 0, b2, nullptr, nullptr, S2, M, 160000, 64);
    gemm_nt<true><<<dim3(M / BM, (67735 + BN - 1) / BN), 256, 0, stream>>>(
        Y3, W3, nullptr, 0, b3, nullptr, nullptr, S3, M, 67735, 16);

    // per-token target logits
    extract_kernel<<<256, 256, 0, stream>>>(Y0, Y1, Y2, Y3, target,
                                            W0, b0, W1, b1, W2, b2, W3, b3,
                                            cw, cb, headlogit, taillogit);

    // final loss
    finalize_kernel<<<1, 256, 0, stream>>>(S0, S1, S2, S3, target,
                                           headlogit, taillogit, out);
}

// Round 2
// 899.698 us; speedup vs baseline: 1.8017x; 1.8017x over previous
//
#include <hip/hip_runtime.h>
#include <math.h>

typedef short short8 __attribute__((ext_vector_type(8)));
typedef float f32x4 __attribute__((ext_vector_type(4)));

#define BM 128
#define BN 128
#define BK 64

__device__ __forceinline__ unsigned short f2bf_rne(float f) {
    unsigned u = __float_as_uint(f);
    unsigned r = (u + 0x7fff + ((u >> 16) & 1)) >> 16;
    return (unsigned short)r;
}
__device__ __forceinline__ float bf2f(unsigned short h) {
    return __uint_as_float(((unsigned)h) << 16);
}

__device__ __forceinline__ void load_lds16(const void* g, void* l) {
    __builtin_amdgcn_global_load_lds((const __attribute__((address_space(1))) void*)g,
                                     (__attribute__((address_space(3))) void*)l,
                                     16, 0, 0);
}

// C = A(bf16) * B(fp32->bf16)^T ; A:[M][lda] bf16, B rows [n][ldb] fp32.
// LDS layout: [kgroup(8)][row(128)][8 bf16] granules of 16B.
// MODE 0: store C bf16 [M][ldc], zeros for n in [nreal, ldc).
// MODE 1: rowsum of exp(c + bias) atomically added into S[m]; cols n >= N excluded.
template<int MODE>
__global__ __launch_bounds__(256) void mfma_gemm(
    const unsigned short* __restrict__ A, int lda,
    const float* __restrict__ B0, const float* __restrict__ B1, int nsplit,
    int ldb, int kreal,
    const float* __restrict__ bias0, const float* __restrict__ bias1,
    unsigned short* __restrict__ C, int ldc, int nreal,
    float* __restrict__ S,
    int N, int K)
{
    __shared__ unsigned short As[8192];   // 16 KB
    __shared__ unsigned short Bs[8192];   // 16 KB

    const int tid = threadIdx.x;
    const int w = tid >> 6;          // wave 0..3
    const int l = tid & 63;
    const int m0 = blockIdx.x * BM;
    const int n0 = blockIdx.y * BN;
    const int wm = (w >> 1) * 64;    // wave tile origin in m
    const int wn = (w & 1) * 64;     // wave tile origin in n
    const int lane16 = l & 15;
    const int quad = l >> 4;

    // ---- A staging constants (global_load_lds, 4 granule-rows per wave) ----
    const unsigned short* aptr[4];
    int ag_base[4];
#pragma unroll
    for (int i = 0; i < 4; ++i) {
        const int g = w * 256 + i * 64 + l;          // granule id 0..1023
        const int kg = g >> 7;                       // k-group 0..7
        const int m = g & 127;                       // row in tile
        aptr[i] = A + (size_t)(m0 + m) * lda + kg * 8;
        ag_base[i] = (w * 256 + i * 64) * 8;         // ushort offset of wave-uniform dst
    }

    // ---- B staging constants (fp32 load + cvt + ds_write) ----
    const int bn = tid >> 1;                          // row in tile 0..127
    const int bhalf = tid & 1;                        // covers k-quads half*8+j
    int brow = n0 + bn;
    if (brow > N - 1) brow = N - 1;
    const float* brow_ptr = (B1 != nullptr && brow >= nsplit)
                          ? (B1 + (size_t)(brow - nsplit) * ldb)
                          : (B0 + (size_t)brow * ldb);

    f32x4 acc[4][4] = {};

    for (int k0 = 0; k0 < K; k0 += BK) {
        __syncthreads();   // previous iteration's LDS reads complete
        // A: async global->LDS, 16B per lane
#pragma unroll
        for (int i = 0; i < 4; ++i)
            load_lds16(aptr[i] + k0, (void*)&As[ag_base[i]]);
        // B: fp32 global -> bf16 (truncate) -> LDS
#pragma unroll
        for (int j = 0; j < 8; ++j) {
            const int kq = bhalf * 8 + j;             // fp32-quad index in row
            int koff = k0 + kq * 4;
            if (koff > kreal - 4) koff = kreal - 4;   // clamp (A k-padding is zero)
            const float4 v = *(const float4*)(brow_ptr + koff);
            const unsigned px = __builtin_amdgcn_perm(__float_as_uint(v.y), __float_as_uint(v.x), 0x07060302);
            const unsigned py = __builtin_amdgcn_perm(__float_as_uint(v.w), __float_as_uint(v.z), 0x07060302);
            const int gran = (kq >> 1) * 128 + bn;
            *(uint2*)&Bs[gran * 8 + (kq & 1) * 4] = make_uint2(px, py);
        }
        __syncthreads();

#pragma unroll
        for (int kk = 0; kk < 2; ++kk) {
            const int kgb = kk * 4 + quad;
            short8 af[4], bfr[4];
#pragma unroll
            for (int mi = 0; mi < 4; ++mi)
                af[mi] = *(const short8*)&As[(kgb * 128 + wm + mi * 16 + lane16) * 8];
#pragma unroll
            for (int ni = 0; ni < 4; ++ni)
                bfr[ni] = *(const short8*)&Bs[(kgb * 128 + wn + ni * 16 + lane16) * 8];
#pragma unroll
            for (int mi = 0; mi < 4; ++mi)
#pragma unroll
                for (int ni = 0; ni < 4; ++ni)
                    acc[mi][ni] = __builtin_amdgcn_mfma_f32_16x16x32_bf16(
                        af[mi], bfr[ni], acc[mi][ni], 0, 0, 0);
        }
    }

    if (MODE == 1) {
        float bias[4];
        bool valid[4];
#pragma unroll
        for (int ni = 0; ni < 4; ++ni) {
            const int n = n0 + wn + ni * 16 + lane16;
            valid[ni] = (n < N);
            bias[ni] = 0.f;
            if (valid[ni])
                bias[ni] = (B1 != nullptr && n >= nsplit) ? bias1[n - nsplit] : bias0[n];
        }
#pragma unroll
        for (int mi = 0; mi < 4; ++mi) {
#pragma unroll
            for (int r = 0; r < 4; ++r) {
                float s = 0.f;
#pragma unroll
                for (int ni = 0; ni < 4; ++ni)
                    if (valid[ni]) s += __expf(acc[mi][ni][r] + bias[ni]);
#pragma unroll
                for (int off = 1; off < 16; off <<= 1)
                    s += __shfl_xor(s, off, 64);
                if (lane16 == 0)
                    atomicAdd(&S[m0 + wm + mi * 16 + quad * 4 + r], s);
            }
        }
    } else {
#pragma unroll
        for (int mi = 0; mi < 4; ++mi)
#pragma unroll
            for (int ni = 0; ni < 4; ++ni) {
                const int n = n0 + wn + ni * 16 + lane16;
                if (n < ldc) {
#pragma unroll
                    for (int r = 0; r < 4; ++r) {
                        const int m = m0 + wm + mi * 16 + quad * 4 + r;
                        const float v = (n < nreal) ? acc[mi][ni][r] : 0.f;
                        C[(size_t)m * ldc + n] = f2bf_rne(v);
                    }
                }
            }
    }
}

__global__ void zero_kernel(float* p, int n)
{
    int i = blockIdx.x * blockDim.x + threadIdx.x;
    if (i < n) p[i] = 0.f;
}

__global__ void cvt_f32_bf16(const float* __restrict__ in, unsigned short* __restrict__ out, int n4)
{
    int i = blockIdx.x * blockDim.x + threadIdx.x;
    if (i < n4) {
        const float4 v = *(const float4*)(in + (size_t)i * 4);
        ushort4 h;
        h.x = f2bf_rne(v.x); h.y = f2bf_rne(v.y);
        h.z = f2bf_rne(v.z); h.w = f2bf_rne(v.w);
        *(ushort4*)(out + (size_t)i * 4) = h;
    }
}

// one wave per token: head target/cluster logit + tail target logit
__global__ void extract_kernel(const unsigned short* __restrict__ Y0, const unsigned short* __restrict__ Y1,
                               const unsigned short* __restrict__ Y2, const unsigned short* __restrict__ Y3,
                               const int* __restrict__ target,
                               const float* __restrict__ W0, const float* __restrict__ b0,
                               const float* __restrict__ W1, const float* __restrict__ b1,
                               const float* __restrict__ W2, const float* __restrict__ b2,
                               const float* __restrict__ W3, const float* __restrict__ b3,
                               const float* __restrict__ cw, const float* __restrict__ cb,
                               float* __restrict__ headlogit, float* __restrict__ taillogit)
{
    const int token = blockIdx.x * 4 + (threadIdx.x >> 6);
    const int lane = threadIdx.x & 63;
    const int tgt = target[token];
    const int ci = (tgt < 20000) ? 0 : (tgt < 40000) ? 1 : (tgt < 200000) ? 2 : 3;

    {
        const int h = (ci == 0) ? tgt : (20000 + ci - 1);
        const float* row;
        float bb;
        if (h < 20000) { row = W0 + (size_t)h * 1024; bb = b0[h]; }
        else           { row = cw + (size_t)(h - 20000) * 1024; bb = cb[h - 20000]; }
        const unsigned short* y = Y0 + (size_t)token * 1024;
        float s = 0.f;
        for (int k = lane; k < 1024; k += 64) s += bf2f(y[k]) * row[k];
#pragma unroll
        for (int off = 1; off < 64; off <<= 1) s += __shfl_xor(s, off, 64);
        if (lane == 0) headlogit[token] = s + bb;
    }

    float tl = 0.f;
    if (ci > 0) {
        const unsigned short* Y; const float* W; const float* b; int K, ldy, lidx;
        if (ci == 1)      { Y = Y1; W = W1; b = b1; K = 256; ldy = 256; lidx = 20000; }
        else if (ci == 2) { Y = Y2; W = W2; b = b2; K = 64;  ldy = 128; lidx = 40000; }
        else              { Y = Y3; W = W3; b = b3; K = 16;  ldy = 64;  lidx = 200000; }
        const int r = tgt - lidx;
        const unsigned short* y = Y + (size_t)token * ldy;
        const float* row = W + (size_t)r * K;
        float s = 0.f;
        for (int k = lane; k < K; k += 64) s += bf2f(y[k]) * row[k];
#pragma unroll
        for (int off = 1; off < 64; off <<= 1) s += __shfl_xor(s, off, 64);
        tl = s + b[r];
    }
    if (lane == 0) taillogit[token] = tl;
}

__global__ void finalize_kernel(const float* __restrict__ S0, const float* __restrict__ S1,
                                const float* __restrict__ S2, const float* __restrict__ S3,
                                const int* __restrict__ target,
                                const float* __restrict__ headlogit,
                                const float* __restrict__ taillogit,
                                float* __restrict__ out)
{
    __shared__ float red[256];
    const int tid = threadIdx.x;
    float acc = 0.f;
    for (int token = tid; token < 1024; token += 256) {
        const int tgt = target[token];
        const int ci = (tgt < 20000) ? 0 : (tgt < 40000) ? 1 : (tgt < 200000) ? 2 : 3;
        float lp = headlogit[token] - logf(S0[token]);
        if (ci > 0) {
            const float* S = (ci == 1) ? S1 : (ci == 2) ? S2 : S3;
            lp += taillogit[token] - logf(S[token]);
        }
        acc -= lp;
    }
    red[tid] = acc;
    __syncthreads();
    for (int s = 128; s > 0; s >>= 1) {
        if (tid < s) red[tid] += red[tid + s];
        __syncthreads();
    }
    if (tid == 0) out[0] = red[0] * (1.0f / 1024.0f);
}

extern "C" void kernel_launch(void* const* d_in, const int* in_sizes, int n_in,
                              void* d_out, int out_size, void* d_ws, size_t ws_size,
                              hipStream_t stream)
{
    const float* hidden = (const float*)d_in[0];
    const int*   target = (const int*)d_in[1];
    const float* W0 = (const float*)d_in[2];  const float* b0 = (const float*)d_in[3];  const float* P0 = (const float*)d_in[4];
    const float* W1 = (const float*)d_in[5];  const float* b1 = (const float*)d_in[6];  const float* P1 = (const float*)d_in[7];
    const float* W2 = (const float*)d_in[8];  const float* b2 = (const float*)d_in[9];  const float* P2 = (const float*)d_in[10];
    const float* W3 = (const float*)d_in[11]; const float* b3 = (const float*)d_in[12]; const float* P3 = (const float*)d_in[13];
    const float* cw = (const float*)d_in[14]; const float* cb = (const float*)d_in[15];
    float* out = (float*)d_out;

    const int M = 1024;

    // workspace layout (bytes): bf16 buffers first, then fp32 scalars
    char* ws = (char*)d_ws;
    unsigned short* h_bf = (unsigned short*)ws;                 // 1024*1024
    unsigned short* Y0 = h_bf + 1024 * 1024;                    // 1024*1024
    unsigned short* Y1 = Y0 + 1024 * 1024;                      // 1024*256
    unsigned short* Y2 = Y1 + 1024 * 256;                       // 1024*128 (n-pad)
    unsigned short* Y3 = Y2 + 1024 * 128;                       // 1024*64  (n-pad = k-pad of tail3)
    float* S0 = (float*)(Y3 + 1024 * 64);
    float* S1 = S0 + 1024;
    float* S2 = S1 + 1024;
    float* S3 = S2 + 1024;
    float* headlogit = S3 + 1024;
    float* taillogit = headlogit + 1024;

    zero_kernel<<<16, 256, 0, stream>>>(S0, 4096);
    cvt_f32_bf16<<<1024, 256, 0, stream>>>(hidden, h_bf, 1024 * 1024 / 4);

    // ---- projections: Y_i = hidden @ P_i^T  (MODE 0) ----
    mfma_gemm<0><<<dim3(M / BM, 8), 256, 0, stream>>>(
        h_bf, 1024, P0, nullptr, 0, 1024, 1024, nullptr, nullptr,
        Y0, 1024, 1024, nullptr, 1024, 1024);
    mfma_gemm<0><<<dim3(M / BM, 2), 256, 0, stream>>>(
        h_bf, 1024, P1, nullptr, 0, 1024, 1024, nullptr, nullptr,
        Y1, 256, 256, nullptr, 256, 1024);
    mfma_gemm<0><<<dim3(M / BM, 1), 256, 0, stream>>>(
        h_bf, 1024, P2, nullptr, 0, 1024, 1024, nullptr, nullptr,
        Y2, 128, 64, nullptr, 64, 1024);
    mfma_gemm<0><<<dim3(M / BM, 1), 256, 0, stream>>>(
        h_bf, 1024, P3, nullptr, 0, 1024, 1024, nullptr, nullptr,
        Y3, 64, 16, nullptr, 16, 1024);

    // ---- exp-sum GEMMs (MODE 1) ----
    mfma_gemm<1><<<dim3(M / BM, (20003 + BN - 1) / BN), 256, 0, stream>>>(
        Y0, 1024, W0, cw, 20000, 1024, 1024, b0, cb,
        nullptr, 0, 0, S0, 20003, 1024);
    mfma_gemm<1><<<dim3(M / BM, (20000 + BN - 1) / BN), 256, 0, stream>>>(
        Y1, 256, W1, nullptr, 0, 256, 256, b1, nullptr,
        nullptr, 0, 0, S1, 20000, 256);
    mfma_gemm<1><<<dim3(M / BM, (160000 + BN - 1) / BN), 256, 0, stream>>>(
        Y2, 128, W2, nullptr, 0, 64, 64, b2, nullptr,
        nullptr, 0, 0, S2, 160000, 64);
    mfma_gemm<1><<<dim3(M / BM, (67735 + BN - 1) / BN), 256, 0, stream>>>(
        Y3, 64, W3, nullptr, 0, 16, 16, b3, nullptr,
        nullptr, 0, 0, S3, 67735, 64);

    extract_kernel<<<256, 256, 0, stream>>>(Y0, Y1, Y2, Y3, target,
                                            W0, b0, W1, b1, W2, b2, W3, b3,
                                            cw, cb, headlogit, taillogit);

    finalize_kernel<<<1, 256, 0, stream>>>(S0, S1, S2, S3, target,
                                           headlogit, taillogit, out);
}

// Round 3
// 698.670 us; speedup vs baseline: 2.3201x; 1.2877x over previous
//
#include <hip/hip_runtime.h>
#include <math.h>

typedef short short8 __attribute__((ext_vector_type(8)));
typedef float f32x4 __attribute__((ext_vector_type(4)));

#define BM 128
#define BK 64

__device__ __forceinline__ unsigned short f2bf_rne(float f) {
    unsigned u = __float_as_uint(f);
    unsigned r = (u + 0x7fff + ((u >> 16) & 1)) >> 16;
    return (unsigned short)r;
}
__device__ __forceinline__ float bf2f(unsigned short h) {
    return __uint_as_float(((unsigned)h) << 16);
}

__device__ __forceinline__ void load_lds16(const void* g, void* l) {
    __builtin_amdgcn_global_load_lds((const __attribute__((address_space(1))) void*)g,
                                     (__attribute__((address_space(3))) void*)l,
                                     16, 0, 0);
}

// ---------------- projection GEMM (store C bf16) ----------------
// C = A(bf16) * B(fp32->bf16)^T ; LDS granules [kgroup(8)][row(128)][8 bf16].
__global__ __launch_bounds__(256) void proj_gemm(
    const unsigned short* __restrict__ A, int lda,
    const float* __restrict__ B, int ldb, int kreal,
    unsigned short* __restrict__ C, int ldc, int nreal,
    int N, int K)
{
    __shared__ unsigned short As[8192];
    __shared__ unsigned short Bs[8192];

    const int tid = threadIdx.x;
    const int w = tid >> 6;
    const int l = tid & 63;
    const int m0 = blockIdx.x * BM;
    const int n0 = blockIdx.y * 128;
    const int wm = (w >> 1) * 64;
    const int wn = (w & 1) * 64;
    const int lane16 = l & 15;
    const int quad = l >> 4;

    const unsigned short* aptr[4];
    int ag_base[4];
#pragma unroll
    for (int i = 0; i < 4; ++i) {
        const int g = w * 256 + i * 64 + l;
        const int kg = g >> 7;
        const int m = g & 127;
        aptr[i] = A + (size_t)(m0 + m) * lda + kg * 8;
        ag_base[i] = (w * 256 + i * 64) * 8;
    }

    const int bn = tid >> 1;
    const int bhalf = tid & 1;
    int brow = n0 + bn;
    if (brow > N - 1) brow = N - 1;
    const float* brow_ptr = B + (size_t)brow * ldb;

    f32x4 acc[4][4] = {};

    for (int k0 = 0; k0 < K; k0 += BK) {
        __syncthreads();
#pragma unroll
        for (int i = 0; i < 4; ++i)
            load_lds16(aptr[i] + k0, (void*)&As[ag_base[i]]);
#pragma unroll
        for (int j = 0; j < 8; ++j) {
            const int kq = bhalf * 8 + j;
            int koff = k0 + kq * 4;
            if (koff > kreal - 4) koff = kreal - 4;
            const float4 v = *(const float4*)(brow_ptr + koff);
            const unsigned px = __builtin_amdgcn_perm(__float_as_uint(v.y), __float_as_uint(v.x), 0x07060302);
            const unsigned py = __builtin_amdgcn_perm(__float_as_uint(v.w), __float_as_uint(v.z), 0x07060302);
            const int gran = (kq >> 1) * 128 + bn;
            *(uint2*)&Bs[gran * 8 + (kq & 1) * 4] = make_uint2(px, py);
        }
        __syncthreads();

#pragma unroll
        for (int kk = 0; kk < 2; ++kk) {
            const int kgb = kk * 4 + quad;
            short8 af[4], bfr[4];
#pragma unroll
            for (int mi = 0; mi < 4; ++mi)
                af[mi] = *(const short8*)&As[(kgb * 128 + wm + mi * 16 + lane16) * 8];
#pragma unroll
            for (int ni = 0; ni < 4; ++ni)
                bfr[ni] = *(const short8*)&Bs[(kgb * 128 + wn + ni * 16 + lane16) * 8];
#pragma unroll
            for (int mi = 0; mi < 4; ++mi)
#pragma unroll
                for (int ni = 0; ni < 4; ++ni)
                    acc[mi][ni] = __builtin_amdgcn_mfma_f32_16x16x32_bf16(
                        af[mi], bfr[ni], acc[mi][ni], 0, 0, 0);
        }
    }

#pragma unroll
    for (int mi = 0; mi < 4; ++mi)
#pragma unroll
        for (int ni = 0; ni < 4; ++ni) {
            const int n = n0 + wn + ni * 16 + lane16;
            if (n < ldc) {
#pragma unroll
                for (int r = 0; r < 4; ++r) {
                    const int m = m0 + wm + mi * 16 + quad * 4 + r;
                    const float v = (n < nreal) ? acc[mi][ni][r] : 0.f;
                    C[(size_t)m * ldc + n] = f2bf_rne(v);
                }
            }
        }
}

// ---------------- fused exp-sum GEMM (4 clusters, partial-sum output) ----------------
struct ExpDesc {
    const unsigned short* A; int lda;
    const float* B0; const float* B1; int nsplit; int ldb; int kreal;
    const float* bias0; const float* bias1;
    float* part;      // [G][1024] non-atomic partials
    int N; int K; int gy_begin; int slab;
};

__global__ __launch_bounds__(256) void exp_gemm(ExpDesc d0, ExpDesc d1, ExpDesc d2, ExpDesc d3)
{
    __shared__ unsigned short As[8192];
    __shared__ unsigned short Bs[8192];
    __shared__ float buf[128][2];

    const int gy = blockIdx.y;
    ExpDesc d = (gy >= d3.gy_begin) ? d3 : (gy >= d2.gy_begin) ? d2
              : (gy >= d1.gy_begin) ? d1 : d0;

    const int tid = threadIdx.x;
    const int w = tid >> 6;
    const int l = tid & 63;
    const int m0 = blockIdx.x * BM;
    const int wm = (w >> 1) * 64;
    const int wn = (w & 1) * 64;
    const int lane16 = l & 15;
    const int quad = l >> 4;

    const unsigned short* aptr[4];
    int ag_base[4];
#pragma unroll
    for (int i = 0; i < 4; ++i) {
        const int g = w * 256 + i * 64 + l;
        const int kg = g >> 7;
        const int m = g & 127;
        aptr[i] = d.A + (size_t)(m0 + m) * d.lda + kg * 8;
        ag_base[i] = (w * 256 + i * 64) * 8;
    }

    const int bn = tid >> 1;
    const int bhalf = tid & 1;

    const int n_begin = (gy - d.gy_begin) * d.slab;
    const int n_end = min(n_begin + d.slab, d.N);

    float rowsum[4][4] = {};

    for (int n0 = n_begin; n0 < n_end; n0 += 128) {
        int brow = n0 + bn;
        if (brow > d.N - 1) brow = d.N - 1;
        const float* brow_ptr = (d.B1 != nullptr && brow >= d.nsplit)
                              ? (d.B1 + (size_t)(brow - d.nsplit) * d.ldb)
                              : (d.B0 + (size_t)brow * d.ldb);

        f32x4 acc[4][4] = {};

        for (int k0 = 0; k0 < d.K; k0 += BK) {
            __syncthreads();
#pragma unroll
            for (int i = 0; i < 4; ++i)
                load_lds16(aptr[i] + k0, (void*)&As[ag_base[i]]);
#pragma unroll
            for (int j = 0; j < 8; ++j) {
                const int kq = bhalf * 8 + j;
                int koff = k0 + kq * 4;
                if (koff > d.kreal - 4) koff = d.kreal - 4;
                const float4 v = *(const float4*)(brow_ptr + koff);
                const unsigned px = __builtin_amdgcn_perm(__float_as_uint(v.y), __float_as_uint(v.x), 0x07060302);
                const unsigned py = __builtin_amdgcn_perm(__float_as_uint(v.w), __float_as_uint(v.z), 0x07060302);
                const int gran = (kq >> 1) * 128 + bn;
                *(uint2*)&Bs[gran * 8 + (kq & 1) * 4] = make_uint2(px, py);
            }
            __syncthreads();

#pragma unroll
            for (int kk = 0; kk < 2; ++kk) {
                const int kgb = kk * 4 + quad;
                short8 af[4], bfr[4];
#pragma unroll
                for (int mi = 0; mi < 4; ++mi)
                    af[mi] = *(const short8*)&As[(kgb * 128 + wm + mi * 16 + lane16) * 8];
#pragma unroll
                for (int ni = 0; ni < 4; ++ni)
                    bfr[ni] = *(const short8*)&Bs[(kgb * 128 + wn + ni * 16 + lane16) * 8];
#pragma unroll
                for (int mi = 0; mi < 4; ++mi)
#pragma unroll
                    for (int ni = 0; ni < 4; ++ni)
                        acc[mi][ni] = __builtin_amdgcn_mfma_f32_16x16x32_bf16(
                            af[mi], bfr[ni], acc[mi][ni], 0, 0, 0);
            }
        }

        // epilogue: exp + accumulate into register rowsums
        float bias[4];
        bool valid[4];
#pragma unroll
        for (int ni = 0; ni < 4; ++ni) {
            const int n = n0 + wn + ni * 16 + lane16;
            valid[ni] = (n < d.N);
            bias[ni] = 0.f;
            if (valid[ni])
                bias[ni] = (d.B1 != nullptr && n >= d.nsplit) ? d.bias1[n - d.nsplit]
                                                              : d.bias0[n];
        }
#pragma unroll
        for (int mi = 0; mi < 4; ++mi)
#pragma unroll
            for (int r = 0; r < 4; ++r) {
                float s = 0.f;
#pragma unroll
                for (int ni = 0; ni < 4; ++ni)
                    if (valid[ni]) s += __expf(acc[mi][ni][r] + bias[ni]);
                rowsum[mi][r] += s;
            }
    }

    // cross-lane (16) reduce, then cross-wave combine through LDS, non-atomic write
#pragma unroll
    for (int off = 1; off < 16; off <<= 1)
#pragma unroll
        for (int mi = 0; mi < 4; ++mi)
#pragma unroll
            for (int r = 0; r < 4; ++r)
                rowsum[mi][r] += __shfl_xor(rowsum[mi][r], off, 64);

    __syncthreads();   // all LDS reads of Bs/As done before reusing wave slots; buf separate but cheap
    if (lane16 == 0) {
#pragma unroll
        for (int mi = 0; mi < 4; ++mi)
#pragma unroll
            for (int r = 0; r < 4; ++r)
                buf[wm + mi * 16 + quad * 4 + r][wn >> 6] = rowsum[mi][r];
    }
    __syncthreads();
    if (tid < 128)
        d.part[(size_t)(gy - d.gy_begin) * 1024 + m0 + tid] = buf[tid][0] + buf[tid][1];
}

__global__ void cvt_f32_bf16(const float* __restrict__ in, unsigned short* __restrict__ out, int n4)
{
    int i = blockIdx.x * blockDim.x + threadIdx.x;
    if (i < n4) {
        const float4 v = *(const float4*)(in + (size_t)i * 4);
        ushort4 h;
        h.x = f2bf_rne(v.x); h.y = f2bf_rne(v.y);
        h.z = f2bf_rne(v.z); h.w = f2bf_rne(v.w);
        *(ushort4*)(out + (size_t)i * 4) = h;
    }
}

// sum partial slabs: S_c[m] = sum_y part_c[y][m]; grid (4 clusters, 8 m-chunks), 128 thr
__global__ void reduce_part(const float* p0, const float* p1, const float* p2, const float* p3,
                            int g0, int g1, int g2, int g3, float* S)
{
    const int c = blockIdx.x;
    const float* p = (c == 0) ? p0 : (c == 1) ? p1 : (c == 2) ? p2 : p3;
    const int G = (c == 0) ? g0 : (c == 1) ? g1 : (c == 2) ? g2 : g3;
    const int m = blockIdx.y * 128 + threadIdx.x;
    float s = 0.f;
    for (int y = 0; y < G; ++y) s += p[(size_t)y * 1024 + m];
    S[c * 1024 + m] = s;
}

// one wave per token: head target/cluster logit + tail target logit
__global__ void extract_kernel(const unsigned short* __restrict__ Y0, const unsigned short* __restrict__ Y1,
                               const unsigned short* __restrict__ Y2, const unsigned short* __restrict__ Y3,
                               const int* __restrict__ target,
                               const float* __restrict__ W0, const float* __restrict__ b0,
                               const float* __restrict__ W1, const float* __restrict__ b1,
                               const float* __restrict__ W2, const float* __restrict__ b2,
                               const float* __restrict__ W3, const float* __restrict__ b3,
                               const float* __restrict__ cw, const float* __restrict__ cb,
                               float* __restrict__ headlogit, float* __restrict__ taillogit)
{
    const int token = blockIdx.x * 4 + (threadIdx.x >> 6);
    const int lane = threadIdx.x & 63;
    const int tgt = target[token];
    const int ci = (tgt < 20000) ? 0 : (tgt < 40000) ? 1 : (tgt < 200000) ? 2 : 3;

    {
        const int h = (ci == 0) ? tgt : (20000 + ci - 1);
        const float* row;
        float bb;
        if (h < 20000) { row = W0 + (size_t)h * 1024; bb = b0[h]; }
        else           { row = cw + (size_t)(h - 20000) * 1024; bb = cb[h - 20000]; }
        const unsigned short* y = Y0 + (size_t)token * 1024;
        float s = 0.f;
        for (int k = lane; k < 1024; k += 64) s += bf2f(y[k]) * row[k];
#pragma unroll
        for (int off = 1; off < 64; off <<= 1) s += __shfl_xor(s, off, 64);
        if (lane == 0) headlogit[token] = s + bb;
    }

    float tl = 0.f;
    if (ci > 0) {
        const unsigned short* Y; const float* W; const float* b; int K, ldy, lidx;
        if (ci == 1)      { Y = Y1; W = W1; b = b1; K = 256; ldy = 256; lidx = 20000; }
        else if (ci == 2) { Y = Y2; W = W2; b = b2; K = 64;  ldy = 128; lidx = 40000; }
        else              { Y = Y3; W = W3; b = b3; K = 16;  ldy = 64;  lidx = 200000; }
        const int r = tgt - lidx;
        const unsigned short* y = Y + (size_t)token * ldy;
        const float* row = W + (size_t)r * K;
        float s = 0.f;
        for (int k = lane; k < K; k += 64) s += bf2f(y[k]) * row[k];
#pragma unroll
        for (int off = 1; off < 64; off <<= 1) s += __shfl_xor(s, off, 64);
        tl = s + b[r];
    }
    if (lane == 0) taillogit[token] = tl;
}

__global__ void finalize_kernel(const float* __restrict__ S, // S0..S3 contiguous
                                const int* __restrict__ target,
                                const float* __restrict__ headlogit,
                                const float* __restrict__ taillogit,
                                float* __restrict__ out)
{
    __shared__ float red[256];
    const int tid = threadIdx.x;
    float acc = 0.f;
    for (int token = tid; token < 1024; token += 256) {
        const int tgt = target[token];
        const int ci = (tgt < 20000) ? 0 : (tgt < 40000) ? 1 : (tgt < 200000) ? 2 : 3;
        float lp = headlogit[token] - logf(S[token]);
        if (ci > 0)
            lp += taillogit[token] - logf(S[ci * 1024 + token]);
        acc -= lp;
    }
    red[tid] = acc;
    __syncthreads();
    for (int s = 128; s > 0; s >>= 1) {
        if (tid < s) red[tid] += red[tid + s];
        __syncthreads();
    }
    if (tid == 0) out[0] = red[0] * (1.0f / 1024.0f);
}

extern "C" void kernel_launch(void* const* d_in, const int* in_sizes, int n_in,
                              void* d_out, int out_size, void* d_ws, size_t ws_size,
                              hipStream_t stream)
{
    const float* hidden = (const float*)d_in[0];
    const int*   target = (const int*)d_in[1];
    const float* W0 = (const float*)d_in[2];  const float* b0 = (const float*)d_in[3];  const float* P0 = (const float*)d_in[4];
    const float* W1 = (const float*)d_in[5];  const float* b1 = (const float*)d_in[6];  const float* P1 = (const float*)d_in[7];
    const float* W2 = (const float*)d_in[8];  const float* b2 = (const float*)d_in[9];  const float* P2 = (const float*)d_in[10];
    const float* W3 = (const float*)d_in[11]; const float* b3 = (const float*)d_in[12]; const float* P3 = (const float*)d_in[13];
    const float* cw = (const float*)d_in[14]; const float* cb = (const float*)d_in[15];
    float* out = (float*)d_out;

    const int M = 1024;

    // ---- workspace layout ----
    char* ws = (char*)d_ws;
    unsigned short* h_bf = (unsigned short*)ws;                 // 1024*1024 bf16 (2 MB)
    unsigned short* Y0 = h_bf + 1024 * 1024;                    // 2 MB
    unsigned short* Y1 = Y0 + 1024 * 1024;                      // 512 KB
    unsigned short* Y2 = Y1 + 1024 * 256;                       // 256 KB (n-padded to 128)
    unsigned short* Y3 = Y2 + 1024 * 128;                       // 128 KB (n-pad 64 = k-pad of tail3)
    float* S = (float*)(Y3 + 1024 * 64);                        // 4 x 1024
    float* headlogit = S + 4 * 1024;
    float* taillogit = headlogit + 1024;
    // partial buffers overlay h_bf (dead after projections; stream-ordered)
    const int G0 = 79, G1 = 40, G2 = 157, G3 = 67;              // slab counts
    float* part0 = (float*)h_bf;                                // 79*4KB
    float* part1 = part0 + (size_t)G0 * 1024;                   // 40*4KB
    float* part2 = part1 + (size_t)G1 * 1024;                   // 157*4KB
    float* part3 = part2 + (size_t)G2 * 1024;                   // 67*4KB  (total 1.34 MB < 2 MB)

    cvt_f32_bf16<<<1024, 256, 0, stream>>>(hidden, h_bf, 1024 * 1024 / 4);

    // ---- projections: Y_i = hidden @ P_i^T ----
    proj_gemm<<<dim3(M / BM, 8), 256, 0, stream>>>(h_bf, 1024, P0, 1024, 1024, Y0, 1024, 1024, 1024, 1024);
    proj_gemm<<<dim3(M / BM, 2), 256, 0, stream>>>(h_bf, 1024, P1, 1024, 1024, Y1, 256, 256, 256, 1024);
    proj_gemm<<<dim3(M / BM, 1), 256, 0, stream>>>(h_bf, 1024, P2, 1024, 1024, Y2, 128, 64, 64, 1024);
    proj_gemm<<<dim3(M / BM, 1), 256, 0, stream>>>(h_bf, 1024, P3, 1024, 1024, Y3, 64, 16, 16, 1024);

    // ---- fused exp-sum GEMMs ----
    ExpDesc d0 = { Y0, 1024, W0, cw, 20000, 1024, 1024, b0, cb, part0, 20003, 1024, 0,              256 };
    ExpDesc d1 = { Y1, 256,  W1, nullptr, 0,  256,  256, b1, nullptr, part1, 20000, 256,  G0,           512 };
    ExpDesc d2 = { Y2, 128,  W2, nullptr, 0,   64,   64, b2, nullptr, part2, 160000, 64,  G0 + G1,      1024 };
    ExpDesc d3 = { Y3, 64,   W3, nullptr, 0,   16,   16, b3, nullptr, part3, 67735,  64,  G0 + G1 + G2, 1024 };
    exp_gemm<<<dim3(M / BM, G0 + G1 + G2 + G3), 256, 0, stream>>>(d0, d1, d2, d3);

    reduce_part<<<dim3(4, 8), 128, 0, stream>>>(part0, part1, part2, part3, G0, G1, G2, G3, S);

    extract_kernel<<<256, 256, 0, stream>>>(Y0, Y1, Y2, Y3, target,
                                            W0, b0, W1, b1, W2, b2, W3, b3,
                                            cw, cb, headlogit, taillogit);

    finalize_kernel<<<1, 256, 0, stream>>>(S, target, headlogit, taillogit, out);
}

// Round 4
// 519.043 us; speedup vs baseline: 3.1231x; 1.3461x over previous
//
#include <hip/hip_runtime.h>
#include <math.h>

typedef short short8 __attribute__((ext_vector_type(8)));
typedef float f32x4 __attribute__((ext_vector_type(4)));

#define BM 128
#define BK 64

__device__ __forceinline__ unsigned short f2bf_rne(float f) {
    unsigned u = __float_as_uint(f);
    unsigned r = (u + 0x7fff + ((u >> 16) & 1)) >> 16;
    return (unsigned short)r;
}
__device__ __forceinline__ float bf2f(unsigned short h) {
    return __uint_as_float(((unsigned)h) << 16);
}

__device__ __forceinline__ void load_lds16(const void* g, void* l) {
    __builtin_amdgcn_global_load_lds((const __attribute__((address_space(1))) void*)g,
                                     (__attribute__((address_space(3))) void*)l,
                                     16, 0, 0);
}

// ---------------- fused projection GEMM (4 outputs, one launch) ----------------
struct ProjDesc {
    const float* B;            // fp32 P matrix [N][1024]
    unsigned short* C;         // bf16 out [1024][ldc]
    int ldc; int nreal; int N; int gy_begin;
};

__global__ __launch_bounds__(256) void proj_gemm(
    const unsigned short* __restrict__ A,   // h_bf [1024][1024]
    ProjDesc p0, ProjDesc p1, ProjDesc p2, ProjDesc p3)
{
    __shared__ unsigned short As[8192];
    __shared__ unsigned short Bs[8192];

    const int gy = blockIdx.y;
    ProjDesc p = (gy >= p3.gy_begin) ? p3 : (gy >= p2.gy_begin) ? p2
               : (gy >= p1.gy_begin) ? p1 : p0;

    const int tid = threadIdx.x;
    const int w = tid >> 6;
    const int l = tid & 63;
    const int m0 = blockIdx.x * BM;
    const int n0 = (gy - p.gy_begin) * 128;
    const int wm = (w >> 1) * 64;
    const int wn = (w & 1) * 64;
    const int lane16 = l & 15;
    const int quad = l >> 4;

    const unsigned short* aptr[4];
    int ag_base[4];
#pragma unroll
    for (int i = 0; i < 4; ++i) {
        const int g = w * 256 + i * 64 + l;
        aptr[i] = A + (size_t)(m0 + (g & 127)) * 1024 + (g >> 7) * 8;
        ag_base[i] = (w * 256 + i * 64) * 8;
    }

    const int bn = tid >> 1;
    const int bhalf = tid & 1;
    int brow = n0 + bn;
    if (brow > p.N - 1) brow = p.N - 1;
    const float* brow_ptr = p.B + (size_t)brow * 1024;

    f32x4 acc[4][4] = {};

    for (int k0 = 0; k0 < 1024; k0 += BK) {
        __syncthreads();
#pragma unroll
        for (int i = 0; i < 4; ++i)
            load_lds16(aptr[i] + k0, (void*)&As[ag_base[i]]);
#pragma unroll
        for (int j = 0; j < 8; ++j) {
            const int kq = bhalf * 8 + j;
            const float4 v = *(const float4*)(brow_ptr + k0 + kq * 4);
            const unsigned px = __builtin_amdgcn_perm(__float_as_uint(v.y), __float_as_uint(v.x), 0x07060302);
            const unsigned py = __builtin_amdgcn_perm(__float_as_uint(v.w), __float_as_uint(v.z), 0x07060302);
            const int gran = (kq >> 1) * 128 + bn;
            *(uint2*)&Bs[gran * 8 + (kq & 1) * 4] = make_uint2(px, py);
        }
        __syncthreads();

#pragma unroll
        for (int kk = 0; kk < 2; ++kk) {
            const int kgb = kk * 4 + quad;
            short8 af[4], bfr[4];
#pragma unroll
            for (int mi = 0; mi < 4; ++mi)
                af[mi] = *(const short8*)&As[(kgb * 128 + wm + mi * 16 + lane16) * 8];
#pragma unroll
            for (int ni = 0; ni < 4; ++ni)
                bfr[ni] = *(const short8*)&Bs[(kgb * 128 + wn + ni * 16 + lane16) * 8];
#pragma unroll
            for (int mi = 0; mi < 4; ++mi)
#pragma unroll
                for (int ni = 0; ni < 4; ++ni)
                    acc[mi][ni] = __builtin_amdgcn_mfma_f32_16x16x32_bf16(
                        af[mi], bfr[ni], acc[mi][ni], 0, 0, 0);
        }
    }

#pragma unroll
    for (int mi = 0; mi < 4; ++mi)
#pragma unroll
        for (int ni = 0; ni < 4; ++ni) {
            const int n = n0 + wn + ni * 16 + lane16;
            if (n < p.ldc) {
#pragma unroll
                for (int r = 0; r < 4; ++r) {
                    const int m = m0 + wm + mi * 16 + quad * 4 + r;
                    const float v = (n < p.nreal) ? acc[mi][ni][r] : 0.f;
                    p.C[(size_t)m * p.ldc + n] = f2bf_rne(v);
                }
            }
        }
}

// ---------------- fused exp-sum GEMM ----------------
struct ExpDesc {
    const unsigned short* A; int lda;
    const unsigned short* Wbf;                 // bf16 weights (PRECVT path)
    const float* B0; const float* B1; int nsplit; int ldb; int kreal;
    const float* bias0; const float* bias1;
    float* part;                               // [G][1024] non-atomic partials
    int N; int K; int gy_begin; int slab;
};

// BSRC 0: B from pre-converted bf16 via global_load_lds. BSRC 1: fp32 B + VALU cvt.
template<int BSRC>
__global__ __launch_bounds__(256) void exp_gemm(ExpDesc d0, ExpDesc d1, ExpDesc d2, ExpDesc d3)
{
    __shared__ unsigned short As[8192];
    __shared__ unsigned short Bs[8192];
    __shared__ float buf[128][2];

    const int gy = blockIdx.y;
    ExpDesc d = (gy >= d3.gy_begin) ? d3 : (gy >= d2.gy_begin) ? d2
              : (gy >= d1.gy_begin) ? d1 : d0;

    const int tid = threadIdx.x;
    const int w = tid >> 6;
    const int l = tid & 63;
    const int m0 = blockIdx.x * BM;
    const int wm = (w >> 1) * 64;
    const int wn = (w & 1) * 64;
    const int lane16 = l & 15;
    const int quad = l >> 4;

    const unsigned short* aptr[4];
    int ag_base[4];
    int brow_g[4];
#pragma unroll
    for (int i = 0; i < 4; ++i) {
        const int g = w * 256 + i * 64 + l;
        aptr[i] = d.A + (size_t)(m0 + (g & 127)) * d.lda + (g >> 7) * 8;
        ag_base[i] = (w * 256 + i * 64) * 8;
        brow_g[i] = g;   // same granule decomposition for B
    }

    const int bn = tid >> 1;
    const int bhalf = tid & 1;

    const int n_begin = (gy - d.gy_begin) * d.slab;
    const int n_end = min(n_begin + d.slab, d.N);

    float rowsum[4][4] = {};

    for (int n0 = n_begin; n0 < n_end; n0 += 128) {
        const unsigned short* bptr[4];
        const float* brow_ptr;
        if constexpr (BSRC == 0) {
#pragma unroll
            for (int i = 0; i < 4; ++i) {
                int br = n0 + (brow_g[i] & 127);
                if (br > d.N - 1) br = d.N - 1;
                bptr[i] = d.Wbf + (size_t)br * d.ldb + (brow_g[i] >> 7) * 8;
            }
        } else {
            int br = n0 + bn;
            if (br > d.N - 1) br = d.N - 1;
            brow_ptr = (d.B1 != nullptr && br >= d.nsplit)
                     ? (d.B1 + (size_t)(br - d.nsplit) * d.ldb)
                     : (d.B0 + (size_t)br * d.ldb);
        }

        f32x4 acc[4][4] = {};

        for (int k0 = 0; k0 < d.K; k0 += BK) {
            __syncthreads();
#pragma unroll
            for (int i = 0; i < 4; ++i)
                load_lds16(aptr[i] + k0, (void*)&As[ag_base[i]]);
            if constexpr (BSRC == 0) {
#pragma unroll
                for (int i = 0; i < 4; ++i)
                    load_lds16(bptr[i] + k0, (void*)&Bs[ag_base[i]]);
            } else {
#pragma unroll
                for (int j = 0; j < 8; ++j) {
                    const int kq = bhalf * 8 + j;
                    int koff = k0 + kq * 4;
                    if (koff > d.kreal - 4) koff = d.kreal - 4;
                    const float4 v = *(const float4*)(brow_ptr + koff);
                    const unsigned px = __builtin_amdgcn_perm(__float_as_uint(v.y), __float_as_uint(v.x), 0x07060302);
                    const unsigned py = __builtin_amdgcn_perm(__float_as_uint(v.w), __float_as_uint(v.z), 0x07060302);
                    const int gran = (kq >> 1) * 128 + bn;
                    *(uint2*)&Bs[gran * 8 + (kq & 1) * 4] = make_uint2(px, py);
                }
            }
            __syncthreads();

#pragma unroll
            for (int kk = 0; kk < 2; ++kk) {
                const int kgb = kk * 4 + quad;
                short8 af[4], bfr[4];
#pragma unroll
                for (int mi = 0; mi < 4; ++mi)
                    af[mi] = *(const short8*)&As[(kgb * 128 + wm + mi * 16 + lane16) * 8];
#pragma unroll
                for (int ni = 0; ni < 4; ++ni)
                    bfr[ni] = *(const short8*)&Bs[(kgb * 128 + wn + ni * 16 + lane16) * 8];
#pragma unroll
                for (int mi = 0; mi < 4; ++mi)
#pragma unroll
                    for (int ni = 0; ni < 4; ++ni)
                        acc[mi][ni] = __builtin_amdgcn_mfma_f32_16x16x32_bf16(
                            af[mi], bfr[ni], acc[mi][ni], 0, 0, 0);
            }
        }

        float bias[4];
        bool valid[4];
#pragma unroll
        for (int ni = 0; ni < 4; ++ni) {
            const int n = n0 + wn + ni * 16 + lane16;
            valid[ni] = (n < d.N);
            bias[ni] = 0.f;
            if (valid[ni])
                bias[ni] = (d.bias1 != nullptr && n >= d.nsplit) ? d.bias1[n - d.nsplit]
                                                                 : d.bias0[n];
        }
#pragma unroll
        for (int mi = 0; mi < 4; ++mi)
#pragma unroll
            for (int r = 0; r < 4; ++r) {
                float s = 0.f;
#pragma unroll
                for (int ni = 0; ni < 4; ++ni)
                    if (valid[ni]) s += __expf(acc[mi][ni][r] + bias[ni]);
                rowsum[mi][r] += s;
            }
    }

#pragma unroll
    for (int off = 1; off < 16; off <<= 1)
#pragma unroll
        for (int mi = 0; mi < 4; ++mi)
#pragma unroll
            for (int r = 0; r < 4; ++r)
                rowsum[mi][r] += __shfl_xor(rowsum[mi][r], off, 64);

    __syncthreads();
    if (lane16 == 0) {
#pragma unroll
        for (int mi = 0; mi < 4; ++mi)
#pragma unroll
            for (int r = 0; r < 4; ++r)
                buf[wm + mi * 16 + quad * 4 + r][wn >> 6] = rowsum[mi][r];
    }
    __syncthreads();
    if (tid < 128)
        d.part[(size_t)(gy - d.gy_begin) * 1024 + m0 + tid] = buf[tid][0] + buf[tid][1];
}

__global__ void cvt_f32_bf16(const float* __restrict__ in, unsigned short* __restrict__ out, int n4)
{
    int i = blockIdx.x * blockDim.x + threadIdx.x;
    if (i < n4) {
        const float4 v = *(const float4*)(in + (size_t)i * 4);
        ushort4 h;
        h.x = f2bf_rne(v.x); h.y = f2bf_rne(v.y);
        h.z = f2bf_rne(v.z); h.w = f2bf_rne(v.w);
        *(ushort4*)(out + (size_t)i * 4) = h;
    }
}

// one fused pass: W0+cw -> Wb0 (20003x1024), W1 -> Wb1, W2 -> Wb2, W3 -> Wb3 (pad K 16->64)
__global__ void cvt_weights(const float* __restrict__ W0, const float* __restrict__ cw,
                            const float* __restrict__ W1, const float* __restrict__ W2,
                            const float* __restrict__ W3,
                            unsigned short* __restrict__ Wb0, unsigned short* __restrict__ Wb1,
                            unsigned short* __restrict__ Wb2, unsigned short* __restrict__ Wb3)
{
    const unsigned i = blockIdx.x * 256 + threadIdx.x;  // float4-quad unit
    const float* src = nullptr;
    unsigned short* dst;
    unsigned dq;
    bool zero = false;
    if (i < 5120000u) {                       // W0: 20000 x 1024
        src = W0 + (size_t)i * 4; dst = Wb0; dq = i;
    } else if (i < 5120768u) {                // cw: 3 x 1024 appended
        const unsigned j = i - 5120000u;
        src = cw + (size_t)j * 4; dst = Wb0; dq = 5120000u + j;
    } else if (i < 6400768u) {                // W1: 20000 x 256
        const unsigned j = i - 5120768u;
        src = W1 + (size_t)j * 4; dst = Wb1; dq = j;
    } else if (i < 8960768u) {                // W2: 160000 x 64
        const unsigned j = i - 6400768u;
        src = W2 + (size_t)j * 4; dst = Wb2; dq = j;
    } else if (i < 10044528u) {               // W3: 67735 x 16 -> pad 64
        const unsigned j = i - 8960768u;
        const unsigned row = j >> 4, kq = j & 15u;
        dst = Wb3; dq = j;
        if (kq < 4u) src = W3 + ((size_t)row * 4 + kq) * 4;
        else zero = true;
    } else return;

    ushort4 h = make_ushort4(0, 0, 0, 0);
    if (!zero) {
        const float4 v = *(const float4*)src;
        h.x = f2bf_rne(v.x); h.y = f2bf_rne(v.y);
        h.z = f2bf_rne(v.z); h.w = f2bf_rne(v.w);
    }
    *(ushort4*)(dst + (size_t)dq * 4) = h;
}

__global__ void reduce_part(const float* p0, const float* p1, const float* p2, const float* p3,
                            int g0, int g1, int g2, int g3, float* S)
{
    const int c = blockIdx.x;
    const float* p = (c == 0) ? p0 : (c == 1) ? p1 : (c == 2) ? p2 : p3;
    const int G = (c == 0) ? g0 : (c == 1) ? g1 : (c == 2) ? g2 : g3;
    const int m = blockIdx.y * 128 + threadIdx.x;
    float s = 0.f;
    for (int y = 0; y < G; ++y) s += p[(size_t)y * 1024 + m];
    S[c * 1024 + m] = s;
}

__global__ void extract_kernel(const unsigned short* __restrict__ Y0, const unsigned short* __restrict__ Y1,
                               const unsigned short* __restrict__ Y2, const unsigned short* __restrict__ Y3,
                               const int* __restrict__ target,
                               const float* __restrict__ W0, const float* __restrict__ b0,
                               const float* __restrict__ W1, const float* __restrict__ b1,
                               const float* __restrict__ W2, const float* __restrict__ b2,
                               const float* __restrict__ W3, const float* __restrict__ b3,
                               const float* __restrict__ cw, const float* __restrict__ cb,
                               float* __restrict__ headlogit, float* __restrict__ taillogit)
{
    const int token = blockIdx.x * 4 + (threadIdx.x >> 6);
    const int lane = threadIdx.x & 63;
    const int tgt = target[token];
    const int ci = (tgt < 20000) ? 0 : (tgt < 40000) ? 1 : (tgt < 200000) ? 2 : 3;

    {
        const int h = (ci == 0) ? tgt : (20000 + ci - 1);
        const float* row;
        float bb;
        if (h < 20000) { row = W0 + (size_t)h * 1024; bb = b0[h]; }
        else           { row = cw + (size_t)(h - 20000) * 1024; bb = cb[h - 20000]; }
        const unsigned short* y = Y0 + (size_t)token * 1024;
        float s = 0.f;
        for (int k = lane; k < 1024; k += 64) s += bf2f(y[k]) * row[k];
#pragma unroll
        for (int off = 1; off < 64; off <<= 1) s += __shfl_xor(s, off, 64);
        if (lane == 0) headlogit[token] = s + bb;
    }

    float tl = 0.f;
    if (ci > 0) {
        const unsigned short* Y; const float* W; const float* b; int K, ldy, lidx;
        if (ci == 1)      { Y = Y1; W = W1; b = b1; K = 256; ldy = 256; lidx = 20000; }
        else if (ci == 2) { Y = Y2; W = W2; b = b2; K = 64;  ldy = 128; lidx = 40000; }
        else              { Y = Y3; W = W3; b = b3; K = 16;  ldy = 64;  lidx = 200000; }
        const int r = tgt - lidx;
        const unsigned short* y = Y + (size_t)token * ldy;
        const float* row = W + (size_t)r * K;
        float s = 0.f;
        for (int k = lane; k < K; k += 64) s += bf2f(y[k]) * row[k];
#pragma unroll
        for (int off = 1; off < 64; off <<= 1) s += __shfl_xor(s, off, 64);
        tl = s + b[r];
    }
    if (lane == 0) taillogit[token] = tl;
}

__global__ void finalize_kernel(const float* __restrict__ S,
                                const int* __restrict__ target,
                                const float* __restrict__ headlogit,
                                const float* __restrict__ taillogit,
                                float* __restrict__ out)
{
    __shared__ float red[256];
    const int tid = threadIdx.x;
    float acc = 0.f;
    for (int token = tid; token < 1024; token += 256) {
        const int tgt = target[token];
        const int ci = (tgt < 20000) ? 0 : (tgt < 40000) ? 1 : (tgt < 200000) ? 2 : 3;
        float lp = headlogit[token] - logf(S[token]);
        if (ci > 0)
            lp += taillogit[token] - logf(S[ci * 1024 + token]);
        acc -= lp;
    }
    red[tid] = acc;
    __syncthreads();
    for (int s = 128; s > 0; s >>= 1) {
        if (tid < s) red[tid] += red[tid + s];
        __syncthreads();
    }
    if (tid == 0) out[0] = red[0] * (1.0f / 1024.0f);
}

extern "C" void kernel_launch(void* const* d_in, const int* in_sizes, int n_in,
                              void* d_out, int out_size, void* d_ws, size_t ws_size,
                              hipStream_t stream)
{
    const float* hidden = (const float*)d_in[0];
    const int*   target = (const int*)d_in[1];
    const float* W0 = (const float*)d_in[2];  const float* b0 = (const float*)d_in[3];  const float* P0 = (const float*)d_in[4];
    const float* W1 = (const float*)d_in[5];  const float* b1 = (const float*)d_in[6];  const float* P1 = (const float*)d_in[7];
    const float* W2 = (const float*)d_in[8];  const float* b2 = (const float*)d_in[9];  const float* P2 = (const float*)d_in[10];
    const float* W3 = (const float*)d_in[11]; const float* b3 = (const float*)d_in[12]; const float* P3 = (const float*)d_in[13];
    const float* cw = (const float*)d_in[14]; const float* cb = (const float*)d_in[15];
    float* out = (float*)d_out;

    // ---- workspace layout (ushort units) ----
    unsigned short* wsu = (unsigned short*)d_ws;
    unsigned short* h_bf = wsu;                       // 1,048,576  (2 MB; reused for parts/S)
    unsigned short* Y0 = wsu + 1048576;
    unsigned short* Y1 = Y0 + 1048576;
    unsigned short* Y2 = Y1 + 262144;
    unsigned short* Y3 = Y2 + 131072;
    unsigned short* Wb0 = Y3 + 65536;                 // 20003*1024
    unsigned short* Wb1 = Wb0 + 20483072;             // 20000*256
    unsigned short* Wb2 = Wb1 + 5120000;              // 160000*64
    unsigned short* Wb3 = Wb2 + 10240000;             // 67735*64
    const size_t need_bytes = (size_t)(42734016) * 2; // end of Wb3

    const int G0 = 79, G1 = 40, G2 = 157, G3 = 67;
    float* part0 = (float*)h_bf;                      // overlays h_bf (dead after proj)
    float* part1 = part0 + (size_t)G0 * 1024;
    float* part2 = part1 + (size_t)G1 * 1024;
    float* part3 = part2 + (size_t)G2 * 1024;
    float* S = part3 + (size_t)G3 * 1024;             // 4x1024
    float* headlogit = S + 4096;
    float* taillogit = headlogit + 1024;

    const bool precvt = (ws_size >= need_bytes);

    cvt_f32_bf16<<<1024, 256, 0, stream>>>(hidden, h_bf, 1024 * 1024 / 4);
    if (precvt)
        cvt_weights<<<39237, 256, 0, stream>>>(W0, cw, W1, W2, W3, Wb0, Wb1, Wb2, Wb3);

    // ---- fused projections ----
    ProjDesc pr0 = { P0, Y0, 1024, 1024, 1024, 0 };
    ProjDesc pr1 = { P1, Y1, 256,  256,  256,  8 };
    ProjDesc pr2 = { P2, Y2, 128,  64,   64,   10 };
    ProjDesc pr3 = { P3, Y3, 64,   16,   16,   11 };
    proj_gemm<<<dim3(8, 12), 256, 0, stream>>>(h_bf, pr0, pr1, pr2, pr3);

    // ---- fused exp-sum GEMMs ----
    ExpDesc d0 = { Y0, 1024, Wb0, W0, cw,      20000, precvt ? 1024 : 1024, 1024, b0, cb,      part0, 20003,  1024, 0,            256 };
    ExpDesc d1 = { Y1, 256,  Wb1, W1, nullptr, 0,     256,                  256,  b1, nullptr, part1, 20000,  256,  G0,           512 };
    ExpDesc d2 = { Y2, 128,  Wb2, W2, nullptr, 0,     64,                   64,   b2, nullptr, part2, 160000, 64,   G0 + G1,      1024 };
    ExpDesc d3 = { Y3, 64,   Wb3, W3, nullptr, 0,     precvt ? 64 : 16,     16,   b3, nullptr, part3, 67735,  64,   G0 + G1 + G2, 1024 };
    if (precvt)
        exp_gemm<0><<<dim3(8, G0 + G1 + G2 + G3), 256, 0, stream>>>(d0, d1, d2, d3);
    else
        exp_gemm<1><<<dim3(8, G0 + G1 + G2 + G3), 256, 0, stream>>>(d0, d1, d2, d3);

    reduce_part<<<dim3(4, 8), 128, 0, stream>>>(part0, part1, part2, part3, G0, G1, G2, G3, S);

    extract_kernel<<<256, 256, 0, stream>>>(Y0, Y1, Y2, Y3, target,
                                            W0, b0, W1, b1, W2, b2, W3, b3,
                                            cw, cb, headlogit, taillogit);

    finalize_kernel<<<1, 256, 0, stream>>>(S, target, headlogit, taillogit, out);
}

// Round 5
// 486.909 us; speedup vs baseline: 3.3292x; 1.0660x over previous
//
#include <hip/hip_runtime.h>
#include <math.h>

typedef short short8 __attribute__((ext_vector_type(8)));
typedef float f32x4 __attribute__((ext_vector_type(4)));

__device__ __forceinline__ unsigned short f2bf_rne(float f) {
    unsigned u = __float_as_uint(f);
    unsigned r = (u + 0x7fff + ((u >> 16) & 1)) >> 16;
    return (unsigned short)r;
}
__device__ __forceinline__ float bf2f(unsigned short h) {
    return __uint_as_float(((unsigned)h) << 16);
}

__device__ __forceinline__ void load_lds16(const void* g, void* l) {
    __builtin_amdgcn_global_load_lds((const __attribute__((address_space(1))) void*)g,
                                     (__attribute__((address_space(3))) void*)l,
                                     16, 0, 0);
}

// ---------------- prep: all fp32->bf16 conversions + padded biases, one launch ----------------
// unit = one float4/ushort4 quad, grid-stride
__global__ void prep_kernel(const float* __restrict__ hidden,
                            const float* __restrict__ W0, const float* __restrict__ cw,
                            const float* __restrict__ W1, const float* __restrict__ W2,
                            const float* __restrict__ W3,
                            const float* __restrict__ b0, const float* __restrict__ cb,
                            const float* __restrict__ b1, const float* __restrict__ b3,
                            unsigned short* __restrict__ h_bf,
                            unsigned short* __restrict__ Wb0, unsigned short* __restrict__ Wb1,
                            unsigned short* __restrict__ Wb2, unsigned short* __restrict__ Wb3,
                            float* __restrict__ b0p, float* __restrict__ b1p,
                            float* __restrict__ b3p)
{
    const unsigned c0 = 262144u;            // h_bf
    const unsigned c1 = c0 + 5144576u;      // Wb0: 20096 x 256 quads
    const unsigned c2 = c1 + 1286144u;      // Wb1: 20096 x 64
    const unsigned c3 = c2 + 2560000u;      // Wb2: 160000 x 16
    const unsigned c4 = c3 + 1085440u;      // Wb3: 67840 x 16
    const unsigned c5 = c4 + 5024u;         // b0p
    const unsigned c6 = c5 + 5024u;         // b1p
    const unsigned c7 = c6 + 16960u;        // b3p

    for (unsigned i = blockIdx.x * 256u + threadIdx.x; i < c7; i += gridDim.x * 256u) {
        if (i < c4) {
            const float* src = nullptr;
            unsigned short* dst;
            unsigned j;
            if (i < c0) {
                j = i; dst = h_bf; src = hidden + (size_t)j * 4;
            } else if (i < c1) {
                j = i - c0; dst = Wb0;
                const unsigned row = j >> 8, kq = j & 255u;
                if (row < 20000u)      src = W0 + (size_t)row * 1024 + kq * 4;
                else if (row < 20003u) src = cw + (size_t)(row - 20000u) * 1024 + kq * 4;
            } else if (i < c2) {
                j = i - c1; dst = Wb1;
                const unsigned row = j >> 6, kq = j & 63u;
                if (row < 20000u) src = W1 + (size_t)row * 256 + kq * 4;
            } else if (i < c3) {
                j = i - c2; dst = Wb2; src = W2 + (size_t)j * 4;
            } else {
                j = i - c3; dst = Wb3;
                const unsigned row = j >> 4, kq = j & 15u;
                if (row < 67735u && kq < 4u) src = W3 + (size_t)row * 16 + kq * 4;
            }
            ushort4 h = make_ushort4(0, 0, 0, 0);
            if (src) {
                const float4 v = *(const float4*)src;
                h.x = f2bf_rne(v.x); h.y = f2bf_rne(v.y);
                h.z = f2bf_rne(v.z); h.w = f2bf_rne(v.w);
            }
            *(ushort4*)(dst + (size_t)j * 4) = h;
        } else {
            float4 v;
            float* dst;
            unsigned j;
            if (i < c5) {
                j = i - c4; dst = b0p;
                float e[4];
#pragma unroll
                for (int k = 0; k < 4; ++k) {
                    const unsigned idx = j * 4 + k;
                    e[k] = (idx < 20000u) ? b0[idx] : (idx < 20003u) ? cb[idx - 20000u] : -1e30f;
                }
                v = make_float4(e[0], e[1], e[2], e[3]);
            } else if (i < c6) {
                j = i - c5; dst = b1p;
                if (j < 5000u) v = *(const float4*)(b1 + (size_t)j * 4);
                else v = make_float4(-1e30f, -1e30f, -1e30f, -1e30f);
            } else {
                j = i - c6; dst = b3p;
                float e[4];
#pragma unroll
                for (int k = 0; k < 4; ++k) {
                    const unsigned idx = j * 4 + k;
                    e[k] = (idx < 67735u) ? b3[idx] : -1e30f;
                }
                v = make_float4(e[0], e[1], e[2], e[3]);
            }
            *(float4*)(dst + (size_t)j * 4) = v;
        }
    }
}

// ---------------- fused projection GEMM (4 outputs, one launch) ----------------
struct ProjDesc {
    const float* B;            // fp32 P matrix [N][1024]
    unsigned short* C;         // bf16 out [1024][ldc]
    int ldc; int nreal; int N; int gy_begin;
};

__global__ __launch_bounds__(256) void proj_gemm(
    const unsigned short* __restrict__ A,   // h_bf [1024][1024]
    ProjDesc p0, ProjDesc p1, ProjDesc p2, ProjDesc p3)
{
    __shared__ unsigned short As[8192];
    __shared__ unsigned short Bs[8192];

    const int gy = blockIdx.y;
    ProjDesc p = (gy >= p3.gy_begin) ? p3 : (gy >= p2.gy_begin) ? p2
               : (gy >= p1.gy_begin) ? p1 : p0;

    const int tid = threadIdx.x;
    const int w = tid >> 6;
    const int l = tid & 63;
    const int m0 = blockIdx.x * 128;
    const int n0 = (gy - p.gy_begin) * 128;
    const int wm = (w >> 1) * 64;
    const int wn = (w & 1) * 64;
    const int lane16 = l & 15;
    const int quad = l >> 4;

    const unsigned short* aptr[4];
    int ag_base[4];
#pragma unroll
    for (int i = 0; i < 4; ++i) {
        const int g = w * 256 + i * 64 + l;
        aptr[i] = A + (size_t)(m0 + (g & 127)) * 1024 + (g >> 7) * 8;
        ag_base[i] = (w * 256 + i * 64) * 8;
    }

    const int bn = tid >> 1;
    const int bhalf = tid & 1;
    int brow = n0 + bn;
    if (brow > p.N - 1) brow = p.N - 1;
    const float* brow_ptr = p.B + (size_t)brow * 1024;

    f32x4 acc[4][4] = {};

    for (int k0 = 0; k0 < 1024; k0 += 64) {
        __syncthreads();
#pragma unroll
        for (int i = 0; i < 4; ++i)
            load_lds16(aptr[i] + k0, (void*)&As[ag_base[i]]);
#pragma unroll
        for (int j = 0; j < 8; ++j) {
            const int kq = bhalf * 8 + j;
            const float4 v = *(const float4*)(brow_ptr + k0 + kq * 4);
            const unsigned px = __builtin_amdgcn_perm(__float_as_uint(v.y), __float_as_uint(v.x), 0x07060302);
            const unsigned py = __builtin_amdgcn_perm(__float_as_uint(v.w), __float_as_uint(v.z), 0x07060302);
            const int gran = (kq >> 1) * 128 + bn;
            *(uint2*)&Bs[gran * 8 + (kq & 1) * 4] = make_uint2(px, py);
        }
        __syncthreads();

#pragma unroll
        for (int kk = 0; kk < 2; ++kk) {
            const int kgb = kk * 4 + quad;
            short8 af[4], bfr[4];
#pragma unroll
            for (int mi = 0; mi < 4; ++mi)
                af[mi] = *(const short8*)&As[(kgb * 128 + wm + mi * 16 + lane16) * 8];
#pragma unroll
            for (int ni = 0; ni < 4; ++ni)
                bfr[ni] = *(const short8*)&Bs[(kgb * 128 + wn + ni * 16 + lane16) * 8];
#pragma unroll
            for (int mi = 0; mi < 4; ++mi)
#pragma unroll
                for (int ni = 0; ni < 4; ++ni)
                    acc[mi][ni] = __builtin_amdgcn_mfma_f32_16x16x32_bf16(
                        af[mi], bfr[ni], acc[mi][ni], 0, 0, 0);
        }
    }

#pragma unroll
    for (int mi = 0; mi < 4; ++mi)
#pragma unroll
        for (int ni = 0; ni < 4; ++ni) {
            const int n = n0 + wn + ni * 16 + lane16;
            if (n < p.ldc) {
#pragma unroll
                for (int r = 0; r < 4; ++r) {
                    const int m = m0 + wm + mi * 16 + quad * 4 + r;
                    const float v = (n < p.nreal) ? acc[mi][ni][r] : 0.f;
                    p.C[(size_t)m * p.ldc + n] = f2bf_rne(v);
                }
            }
        }
}

// ---------------- pipelined exp-sum GEMM ----------------
// All N padded to x128 with -1e30 bias rows (exp -> 0); bf16 A and B staged via
// global_load_lds with double buffering; one barrier per (n-tile,k-step) iter.
struct ExpDesc {
    const unsigned short* A;
    const unsigned short* W;
    const float* bias;     // padded fp32 bias
    float* part;           // [G][1024]
    int lda; int ldb;
    int Npad; int kshift;  // ksteps = 1<<kshift (K = 64<<kshift)
    int gy_begin; int slab;
};

__global__ __launch_bounds__(256) void exp_gemm(ExpDesc d0, ExpDesc d1, ExpDesc d2, ExpDesc d3)
{
    __shared__ unsigned short As[2][8192];
    __shared__ unsigned short Bs[2][8192];
    __shared__ float buf[128][2];

    const int gy = blockIdx.y;
    ExpDesc d = (gy >= d3.gy_begin) ? d3 : (gy >= d2.gy_begin) ? d2
              : (gy >= d1.gy_begin) ? d1 : d0;

    const int tid = threadIdx.x;
    const int w = tid >> 6;
    const int l = tid & 63;
    const int m0 = blockIdx.x * 128;
    const int wm = (w >> 1) * 64;
    const int wn = (w & 1) * 64;
    const int lane16 = l & 15;
    const int quad = l >> 4;

    const unsigned short* aptr[4];
    size_t boff[4];
    int ag_base[4];
#pragma unroll
    for (int i = 0; i < 4; ++i) {
        const int g = w * 256 + i * 64 + l;
        aptr[i] = d.A + (size_t)(m0 + (g & 127)) * d.lda + (g >> 7) * 8;
        boff[i] = (size_t)(g & 127) * d.ldb + (g >> 7) * 8;
        ag_base[i] = (w * 256 + i * 64) * 8;
    }

    const int n_begin = (gy - d.gy_begin) * d.slab;
    const int n_end = min(n_begin + d.slab, d.Npad);
    const int kshift = d.kshift;
    const int kmask = (1 << kshift) - 1;
    const int T = ((n_end - n_begin) >> 7) << kshift;

    // prologue: stage iter 0 into slot 0
#pragma unroll
    for (int i = 0; i < 4; ++i)
        load_lds16(aptr[i], (void*)&As[0][ag_base[i]]);
    {
        const unsigned short* wb = d.W + (size_t)n_begin * d.ldb;
#pragma unroll
        for (int i = 0; i < 4; ++i)
            load_lds16(wb + boff[i], (void*)&Bs[0][ag_base[i]]);
    }

    f32x4 acc[4][4] = {};
    float rowsum[4][4] = {};
    float biasv[4] = {};

    for (int it = 0; it < T; ++it) {
        const int slot = it & 1;
        __syncthreads();                       // drains loads for this iter's buffers

        if (it + 1 < T) {                      // prefetch iter+1 into other slot
            const int ns = slot ^ 1;
            const int k1 = ((it + 1) & kmask) * 64;
            if (kmask) {
#pragma unroll
                for (int i = 0; i < 4; ++i)
                    load_lds16(aptr[i] + k1, (void*)&As[ns][ag_base[i]]);
            }
            const unsigned short* wb = d.W
                + (size_t)(n_begin + (((it + 1) >> kshift) << 7)) * d.ldb + k1;
#pragma unroll
            for (int i = 0; i < 4; ++i)
                load_lds16(wb + boff[i], (void*)&Bs[ns][ag_base[i]]);
        }

        if ((it & kmask) == 0) {               // prefetch bias for this n-tile
            const int n0 = n_begin + ((it >> kshift) << 7);
#pragma unroll
            for (int ni = 0; ni < 4; ++ni)
                biasv[ni] = d.bias[n0 + wn + ni * 16 + lane16];
        }

        const int sa = kmask ? slot : 0;
#pragma unroll
        for (int kk = 0; kk < 2; ++kk) {
            const int kgb = kk * 4 + quad;
            short8 af[4], bfr[4];
#pragma unroll
            for (int mi = 0; mi < 4; ++mi)
                af[mi] = *(const short8*)&As[sa][(kgb * 128 + wm + mi * 16 + lane16) * 8];
#pragma unroll
            for (int ni = 0; ni < 4; ++ni)
                bfr[ni] = *(const short8*)&Bs[slot][(kgb * 128 + wn + ni * 16 + lane16) * 8];
#pragma unroll
            for (int mi = 0; mi < 4; ++mi)
#pragma unroll
                for (int ni = 0; ni < 4; ++ni)
                    acc[mi][ni] = __builtin_amdgcn_mfma_f32_16x16x32_bf16(
                        af[mi], bfr[ni], acc[mi][ni], 0, 0, 0);
        }

        if ((it & kmask) == kmask) {           // epilogue for completed n-tile
#pragma unroll
            for (int mi = 0; mi < 4; ++mi)
#pragma unroll
                for (int r = 0; r < 4; ++r) {
                    float s = __expf(acc[mi][0][r] + biasv[0]);
                    s += __expf(acc[mi][1][r] + biasv[1]);
                    s += __expf(acc[mi][2][r] + biasv[2]);
                    s += __expf(acc[mi][3][r] + biasv[3]);
                    rowsum[mi][r] += s;
                }
#pragma unroll
            for (int mi = 0; mi < 4; ++mi)
#pragma unroll
                for (int ni = 0; ni < 4; ++ni)
                    acc[mi][ni] = (f32x4){0.f, 0.f, 0.f, 0.f};
        }
    }

#pragma unroll
    for (int off = 1; off < 16; off <<= 1)
#pragma unroll
        for (int mi = 0; mi < 4; ++mi)
#pragma unroll
            for (int r = 0; r < 4; ++r)
                rowsum[mi][r] += __shfl_xor(rowsum[mi][r], off, 64);

    __syncthreads();
    if (lane16 == 0) {
#pragma unroll
        for (int mi = 0; mi < 4; ++mi)
#pragma unroll
            for (int r = 0; r < 4; ++r)
                buf[wm + mi * 16 + quad * 4 + r][wn >> 6] = rowsum[mi][r];
    }
    __syncthreads();
    if (tid < 128)
        d.part[(size_t)(gy - d.gy_begin) * 1024 + m0 + tid] = buf[tid][0] + buf[tid][1];
}

__global__ void reduce_part(const float* p0, const float* p1, const float* p2, const float* p3,
                            int g0, int g1, int g2, int g3, float* S)
{
    const int c = blockIdx.x;
    const float* p = (c == 0) ? p0 : (c == 1) ? p1 : (c == 2) ? p2 : p3;
    const int G = (c == 0) ? g0 : (c == 1) ? g1 : (c == 2) ? g2 : g3;
    const int m = blockIdx.y * 128 + threadIdx.x;
    float s = 0.f;
    for (int y = 0; y < G; ++y) s += p[(size_t)y * 1024 + m];
    S[c * 1024 + m] = s;
}

__global__ void extract_kernel(const unsigned short* __restrict__ Y0, const unsigned short* __restrict__ Y1,
                               const unsigned short* __restrict__ Y2, const unsigned short* __restrict__ Y3,
                               const int* __restrict__ target,
                               const float* __restrict__ W0, const float* __restrict__ b0,
                               const float* __restrict__ W1, const float* __restrict__ b1,
                               const float* __restrict__ W2, const float* __restrict__ b2,
                               const float* __restrict__ W3, const float* __restrict__ b3,
                               const float* __restrict__ cw, const float* __restrict__ cb,
                               float* __restrict__ headlogit, float* __restrict__ taillogit)
{
    const int token = blockIdx.x * 4 + (threadIdx.x >> 6);
    const int lane = threadIdx.x & 63;
    const int tgt = target[token];
    const int ci = (tgt < 20000) ? 0 : (tgt < 40000) ? 1 : (tgt < 200000) ? 2 : 3;

    {
        const int h = (ci == 0) ? tgt : (20000 + ci - 1);
        const float* row;
        float bb;
        if (h < 20000) { row = W0 + (size_t)h * 1024; bb = b0[h]; }
        else           { row = cw + (size_t)(h - 20000) * 1024; bb = cb[h - 20000]; }
        const unsigned short* y = Y0 + (size_t)token * 1024;
        float s = 0.f;
        for (int k = lane; k < 1024; k += 64) s += bf2f(y[k]) * row[k];
#pragma unroll
        for (int off = 1; off < 64; off <<= 1) s += __shfl_xor(s, off, 64);
        if (lane == 0) headlogit[token] = s + bb;
    }

    float tl = 0.f;
    if (ci > 0) {
        const unsigned short* Y; const float* W; const float* b; int K, ldy, lidx;
        if (ci == 1)      { Y = Y1; W = W1; b = b1; K = 256; ldy = 256; lidx = 20000; }
        else if (ci == 2) { Y = Y2; W = W2; b = b2; K = 64;  ldy = 128; lidx = 40000; }
        else              { Y = Y3; W = W3; b = b3; K = 16;  ldy = 64;  lidx = 200000; }
        const int r = tgt - lidx;
        const unsigned short* y = Y + (size_t)token * ldy;
        const float* row = W + (size_t)r * K;
        float s = 0.f;
        for (int k = lane; k < K; k += 64) s += bf2f(y[k]) * row[k];
#pragma unroll
        for (int off = 1; off < 64; off <<= 1) s += __shfl_xor(s, off, 64);
        tl = s + b[r];
    }
    if (lane == 0) taillogit[token] = tl;
}

__global__ void finalize_kernel(const float* __restrict__ S,
                                const int* __restrict__ target,
                                const float* __restrict__ headlogit,
                                const float* __restrict__ taillogit,
                                float* __restrict__ out)
{
    __shared__ float red[256];
    const int tid = threadIdx.x;
    float acc = 0.f;
    for (int token = tid; token < 1024; token += 256) {
        const int tgt = target[token];
        const int ci = (tgt < 20000) ? 0 : (tgt < 40000) ? 1 : (tgt < 200000) ? 2 : 3;
        float lp = headlogit[token] - logf(S[token]);
        if (ci > 0)
            lp += taillogit[token] - logf(S[ci * 1024 + token]);
        acc -= lp;
    }
    red[tid] = acc;
    __syncthreads();
    for (int s = 128; s > 0; s >>= 1) {
        if (tid < s) red[tid] += red[tid + s];
        __syncthreads();
    }
    if (tid == 0) out[0] = red[0] * (1.0f / 1024.0f);
}

extern "C" void kernel_launch(void* const* d_in, const int* in_sizes, int n_in,
                              void* d_out, int out_size, void* d_ws, size_t ws_size,
                              hipStream_t stream)
{
    const float* hidden = (const float*)d_in[0];
    const int*   target = (const int*)d_in[1];
    const float* W0 = (const float*)d_in[2];  const float* b0 = (const float*)d_in[3];  const float* P0 = (const float*)d_in[4];
    const float* W1 = (const float*)d_in[5];  const float* b1 = (const float*)d_in[6];  const float* P1 = (const float*)d_in[7];
    const float* W2 = (const float*)d_in[8];  const float* b2 = (const float*)d_in[9];  const float* P2 = (const float*)d_in[10];
    const float* W3 = (const float*)d_in[11]; const float* b3 = (const float*)d_in[12]; const float* P3 = (const float*)d_in[13];
    const float* cw = (const float*)d_in[14]; const float* cb = (const float*)d_in[15];
    float* out = (float*)d_out;

    // ---- workspace layout (ushort units) ----
    unsigned short* wsu = (unsigned short*)d_ws;
    unsigned short* h_bf = wsu;                       // 1,048,576 (2 MB; parts/S overlay later)
    unsigned short* Y0 = wsu + 1048576;               // 1,048,576
    unsigned short* Y1 = Y0 + 1048576;                // 262,144
    unsigned short* Y2 = Y1 + 262144;                 // 131,072 (ld 128, k-pad)
    unsigned short* Y3 = Y2 + 131072;                 // 65,536  (ld 64, k-pad)
    unsigned short* Wb0 = Y3 + 65536;                 // 20096*1024
    unsigned short* Wb1 = Wb0 + 20578304;             // 20096*256
    unsigned short* Wb2 = Wb1 + 5144576;              // 160000*64
    unsigned short* Wb3 = Wb2 + 10240000;             // 67840*64
    float* b0p = (float*)(Wb3 + 4341760);             // 20096
    float* b1p = b0p + 20096;                         // 20096
    float* b3p = b1p + 20096;                         // 67840

    const int G0 = 40, G1 = 10, G2 = 79, G3 = 34;
    float* part0 = (float*)h_bf;                      // overlays h_bf (dead after proj)
    float* part1 = part0 + (size_t)G0 * 1024;
    float* part2 = part1 + (size_t)G1 * 1024;
    float* part3 = part2 + (size_t)G2 * 1024;
    float* S = part3 + (size_t)G3 * 1024;             // 4x1024
    float* headlogit = S + 4096;
    float* taillogit = headlogit + 1024;

    prep_kernel<<<4096, 256, 0, stream>>>(hidden, W0, cw, W1, W2, W3, b0, cb, b1, b3,
                                          h_bf, Wb0, Wb1, Wb2, Wb3, b0p, b1p, b3p);

    // ---- fused projections ----
    ProjDesc pr0 = { P0, Y0, 1024, 1024, 1024, 0 };
    ProjDesc pr1 = { P1, Y1, 256,  256,  256,  8 };
    ProjDesc pr2 = { P2, Y2, 128,  64,   64,   10 };
    ProjDesc pr3 = { P3, Y3, 64,   16,   16,   11 };
    proj_gemm<<<dim3(8, 12), 256, 0, stream>>>(h_bf, pr0, pr1, pr2, pr3);

    // ---- pipelined exp-sum GEMMs ----
    ExpDesc d0 = { Y0, Wb0, b0p, part0, 1024, 1024, 20096,  4, 0,            512 };
    ExpDesc d1 = { Y1, Wb1, b1p, part1, 256,  256,  20096,  2, G0,           2048 };
    ExpDesc d2 = { Y2, Wb2, b2,  part2, 128,  64,   160000, 0, G0 + G1,      2048 };
    ExpDesc d3 = { Y3, Wb3, b3p, part3, 64,   64,   67840,  0, G0 + G1 + G2, 2048 };
    exp_gemm<<<dim3(8, G0 + G1 + G2 + G3), 256, 0, stream>>>(d0, d1, d2, d3);

    reduce_part<<<dim3(4, 8), 128, 0, stream>>>(part0, part1, part2, part3, G0, G1, G2, G3, S);

    extract_kernel<<<256, 256, 0, stream>>>(Y0, Y1, Y2, Y3, target,
                                            W0, b0, W1, b1, W2, b2, W3, b3,
                                            cw, cb, headlogit, taillogit);

    finalize_kernel<<<1, 256, 0, stream>>>(S, target, headlogit, taillogit, out);
}

// Round 6
// 438.581 us; speedup vs baseline: 3.6960x; 1.1102x over previous
//
#include <hip/hip_runtime.h>
#include <math.h>

typedef short short8 __attribute__((ext_vector_type(8)));
typedef float f32x4 __attribute__((ext_vector_type(4)));
typedef unsigned long long u64;

#define LOG2E 1.4426950408889634f

__device__ __forceinline__ unsigned short f2bf_rne(float f) {
    unsigned u = __float_as_uint(f);
    unsigned r = (u + 0x7fff + ((u >> 16) & 1)) >> 16;
    return (unsigned short)r;
}
__device__ __forceinline__ float bf2f(unsigned short h) {
    return __uint_as_float(((unsigned)h) << 16);
}
__device__ __forceinline__ void load_lds16(const void* g, void* l) {
    __builtin_amdgcn_global_load_lds((const __attribute__((address_space(1))) void*)g,
                                     (__attribute__((address_space(3))) void*)l,
                                     16, 0, 0);
}
// 8 fp32 -> 8 fp8 e4m3 (RNE, saturating), scaled
__device__ __forceinline__ u64 pack8_fp8(const float* v, float s) {
    int lo = 0, hi = 0;
    lo = __builtin_amdgcn_cvt_pk_fp8_f32(v[0] * s, v[1] * s, lo, false);
    lo = __builtin_amdgcn_cvt_pk_fp8_f32(v[2] * s, v[3] * s, lo, true);
    hi = __builtin_amdgcn_cvt_pk_fp8_f32(v[4] * s, v[5] * s, hi, false);
    hi = __builtin_amdgcn_cvt_pk_fp8_f32(v[6] * s, v[7] * s, hi, true);
    return (u64)(unsigned)lo | ((u64)(unsigned)hi << 32);
}

// ---------------- cvt hidden fp32 -> bf16 ----------------
__global__ void cvt_h(const float* __restrict__ in, unsigned short* __restrict__ out)
{
    const int i = blockIdx.x * 256 + threadIdx.x;   // one float4 quad each
    const float4 v = *(const float4*)(in + (size_t)i * 4);
    ushort4 h;
    h.x = f2bf_rne(v.x); h.y = f2bf_rne(v.y);
    h.z = f2bf_rne(v.z); h.w = f2bf_rne(v.w);
    *(ushort4*)(out + (size_t)i * 4) = h;
}

// ---------------- fused prep (weights->fp8 swizzle + biases) + projections ----------------
struct ProjDesc {
    const float* B;            // fp32 P matrix [N][1024]
    unsigned short* Cbf;       // bf16 Y [1024][ldc]
    unsigned char* Cf8;        // fp8 Y, granule-tile layout, Kpad cols
    int ldc; int nreal; int N; int Kpad; int gy_begin;
};

__global__ __launch_bounds__(256) void prepproj(
    const unsigned short* __restrict__ A,   // h_bf [1024][1024]
    ProjDesc p0, ProjDesc p1, ProjDesc p2, ProjDesc p3,
    const float* __restrict__ W0, const float* __restrict__ cw,
    const float* __restrict__ W1, const float* __restrict__ W2,
    const float* __restrict__ W3,
    const float* __restrict__ b0, const float* __restrict__ cb,
    const float* __restrict__ b1, const float* __restrict__ b2,
    const float* __restrict__ b3,
    unsigned char* __restrict__ Wb0, unsigned char* __restrict__ Wb1,
    unsigned char* __restrict__ Wb2, unsigned char* __restrict__ Wb3,
    float* __restrict__ bp)
{
    __shared__ char smem[34816];

    const int tid = threadIdx.x;
    const int bx = blockIdx.x;

    if (bx >= 96) {
        // ---------- copy/convert path (grid-stride) ----------
        // unit = 16 fp32 -> 2 granules (16 fp8 bytes)
        const unsigned E0 = 1286144u;   // W0: 157 tiles * 64 kg2 * 128 r
        const unsigned E1 = 1613824u;   // +W1: 160*16*128
        const unsigned E2 = 2260992u;   // +W2: 1264*4*128
        const unsigned E3 = 2539520u;   // +W3: 544*4*128
        const unsigned E4 = 2607520u;   // +bias: 68000 float4 units
        const unsigned stride = (gridDim.x - 96) * 256u;
        for (unsigned u = (bx - 96) * 256u + tid; u < E4; u += stride) {
            if (u < E3) {
                const float* src = nullptr;
                unsigned char* dstm; unsigned tile, kg2, r, tstride;
                if (u < E0) {
                    tile = u >> 13; const unsigned rem = u & 8191u;
                    kg2 = rem >> 7; r = rem & 127u;
                    const unsigned row = tile * 128u + r;
                    if (row < 20000u)      src = W0 + (size_t)row * 1024 + kg2 * 16;
                    else if (row < 20003u) src = cw + (size_t)(row - 20000u) * 1024 + kg2 * 16;
                    dstm = Wb0; tstride = 131072u;
                } else if (u < E1) {
                    const unsigned j = u - E0;
                    tile = j >> 11; const unsigned rem = j & 2047u;
                    kg2 = rem >> 7; r = rem & 127u;
                    const unsigned row = tile * 128u + r;
                    if (row < 20000u) src = W1 + (size_t)row * 256 + kg2 * 16;
                    dstm = Wb1; tstride = 32768u;
                } else if (u < E2) {
                    const unsigned j = u - E1;
                    tile = j >> 9; kg2 = (j >> 7) & 3u; r = j & 127u;
                    const unsigned row = tile * 128u + r;
                    if (row < 160000u) src = W2 + (size_t)row * 64 + kg2 * 16;
                    dstm = Wb2; tstride = 8192u;
                } else {
                    const unsigned j = u - E2;
                    tile = j >> 9; kg2 = (j >> 7) & 3u; r = j & 127u;
                    const unsigned row = tile * 128u + r;
                    if (kg2 == 0 && row < 67735u) src = W3 + (size_t)row * 16;
                    dstm = Wb3; tstride = 8192u;
                }
                float f[16];
                if (src) {
#pragma unroll
                    for (int q = 0; q < 4; ++q) {
                        const float4 v = *(const float4*)(src + q * 4);
                        f[q * 4 + 0] = v.x; f[q * 4 + 1] = v.y;
                        f[q * 4 + 2] = v.z; f[q * 4 + 3] = v.w;
                    }
                } else {
#pragma unroll
                    for (int q = 0; q < 16; ++q) f[q] = 0.f;
                }
                u64* dst = (u64*)(dstm + (size_t)tile * tstride);
                dst[(2 * kg2) * 128 + r]     = pack8_fp8(f,     16.0f);
                dst[(2 * kg2 + 1) * 128 + r] = pack8_fp8(f + 8, 16.0f);
            } else {
                // padded biases, pre-scaled by log2e; pad rows -> -1e30
                const unsigned idx0 = (u - E3) * 4u;
                float e[4];
#pragma unroll
                for (int j = 0; j < 4; ++j) {
                    const unsigned idx = idx0 + j;
                    float v;
                    if (idx < 20096u) {
                        v = (idx < 20000u) ? b0[idx] * LOG2E
                          : (idx < 20003u) ? cb[idx - 20000u] * LOG2E : -1e30f;
                    } else if (idx < 40576u) {
                        const unsigned i1 = idx - 20096u;
                        v = (i1 < 20000u) ? b1[i1] * LOG2E : -1e30f;
                    } else if (idx < 202368u) {
                        const unsigned i2 = idx - 40576u;
                        v = (i2 < 160000u) ? b2[i2] * LOG2E : -1e30f;
                    } else {
                        const unsigned i3 = idx - 202368u;
                        v = (i3 < 67735u) ? b3[i3] * LOG2E : -1e30f;
                    }
                    e[j] = v;
                }
                *(float4*)(bp + idx0) = make_float4(e[0], e[1], e[2], e[3]);
            }
        }
        return;
    }

    // ---------- projection GEMM path ----------
    unsigned short* As = (unsigned short*)smem;            // [8192] bf16
    unsigned short* Bs = (unsigned short*)(smem + 16384);  // [8192] bf16

    const int mt = bx & 7;
    const int py = bx >> 3;
    ProjDesc p = (py >= p3.gy_begin) ? p3 : (py >= p2.gy_begin) ? p2
               : (py >= p1.gy_begin) ? p1 : p0;

    const int w = tid >> 6;
    const int l = tid & 63;
    const int m0 = mt * 128;
    const int n0 = (py - p.gy_begin) * 128;
    const int wm = (w >> 1) * 64;
    const int wn = (w & 1) * 64;
    const int lane16 = l & 15;
    const int quad = l >> 4;

    const unsigned short* aptr[4];
    int ag_base[4];
#pragma unroll
    for (int i = 0; i < 4; ++i) {
        const int g = w * 256 + i * 64 + l;
        aptr[i] = A + (size_t)(m0 + (g & 127)) * 1024 + (g >> 7) * 8;
        ag_base[i] = (w * 256 + i * 64) * 8;
    }

    const int bn = tid >> 1;
    const int bhalf = tid & 1;
    int brow = n0 + bn;
    if (brow > p.N - 1) brow = p.N - 1;
    const float* brow_ptr = p.B + (size_t)brow * 1024;

    f32x4 acc[4][4] = {};

    for (int k0 = 0; k0 < 1024; k0 += 64) {
        __syncthreads();
#pragma unroll
        for (int i = 0; i < 4; ++i)
            load_lds16(aptr[i] + k0, (void*)&As[ag_base[i]]);
#pragma unroll
        for (int j = 0; j < 8; ++j) {
            const int kq = bhalf * 8 + j;
            const float4 v = *(const float4*)(brow_ptr + k0 + kq * 4);
            const unsigned px = __builtin_amdgcn_perm(__float_as_uint(v.y), __float_as_uint(v.x), 0x07060302);
            const unsigned pyv = __builtin_amdgcn_perm(__float_as_uint(v.w), __float_as_uint(v.z), 0x07060302);
            const int gran = (kq >> 1) * 128 + bn;
            *(uint2*)&Bs[gran * 8 + (kq & 1) * 4] = make_uint2(px, pyv);
        }
        __syncthreads();

#pragma unroll
        for (int kk = 0; kk < 2; ++kk) {
            const int kgb = kk * 4 + quad;
            short8 af[4], bfr[4];
#pragma unroll
            for (int mi = 0; mi < 4; ++mi)
                af[mi] = *(const short8*)&As[(kgb * 128 + wm + mi * 16 + lane16) * 8];
#pragma unroll
            for (int ni = 0; ni < 4; ++ni)
                bfr[ni] = *(const short8*)&Bs[(kgb * 128 + wn + ni * 16 + lane16) * 8];
#pragma unroll
            for (int mi = 0; mi < 4; ++mi)
#pragma unroll
                for (int ni = 0; ni < 4; ++ni)
                    acc[mi][ni] = __builtin_amdgcn_mfma_f32_16x16x32_bf16(
                        af[mi], bfr[ni], acc[mi][ni], 0, 0, 0);
        }
    }

    // epilogue 1: bf16 Y store
#pragma unroll
    for (int mi = 0; mi < 4; ++mi)
#pragma unroll
        for (int ni = 0; ni < 4; ++ni) {
            const int n = n0 + wn + ni * 16 + lane16;
            if (n < p.ldc) {
#pragma unroll
                for (int r = 0; r < 4; ++r) {
                    const int m = m0 + wm + mi * 16 + quad * 4 + r;
                    const float v = (n < p.nreal) ? acc[mi][ni][r] : 0.f;
                    p.Cbf[(size_t)m * p.ldc + n] = f2bf_rne(v);
                }
            }
        }

    // epilogue 2: fp8 Y store in granule-tile layout (scale x4), via LDS bounce
    float* bounce = (float*)smem;                           // [128][66]
    u64* Yout = (u64*)p.Cf8 + (size_t)mt * 16 * p.Kpad;
    for (int c = 0; c < 2; ++c) {
        const int colbase = n0 + c * 64;
        if (colbase >= p.Kpad) break;
        __syncthreads();
        if ((w & 1) == c) {
#pragma unroll
            for (int mi = 0; mi < 4; ++mi)
#pragma unroll
                for (int ni = 0; ni < 4; ++ni) {
                    const int ncol = ni * 16 + lane16;
                    const bool real = (colbase + ncol) < p.nreal;
#pragma unroll
                    for (int r = 0; r < 4; ++r) {
                        const int m = wm + mi * 16 + quad * 4 + r;
                        bounce[m * 66 + ncol] = real ? acc[mi][ni][r] : 0.f;
                    }
                }
        }
        __syncthreads();
#pragma unroll
        for (int i = 0; i < 4; ++i) {
            const int g = i * 256 + tid;
            const int kgl = g >> 7;
            const int m = g & 127;
            float v[8];
#pragma unroll
            for (int j = 0; j < 8; ++j) v[j] = bounce[m * 66 + kgl * 8 + j];
            Yout[((colbase >> 3) + kgl) * 128 + m] = pack8_fp8(v, 4.0f);
        }
    }
}

// ---------------- pipelined fp8 exp-sum GEMM ----------------
struct ExpDesc {
    const unsigned char* A;   // fp8 Y, granule-tile layout
    const unsigned char* W;   // fp8 W, granule-tile layout
    const float* bias;        // padded, pre-scaled by log2e
    float* part;              // [G][1024]
    int Kpad; int ksl; int kmask; int gy_begin; int slab;  // slab in 128-row tiles
};

__global__ __launch_bounds__(256) void exp_gemm(ExpDesc d0, ExpDesc d1, ExpDesc d2, ExpDesc d3)
{
    __shared__ u64 As[2][1024];   // 8 KB each
    __shared__ u64 Bs[2][1024];
    __shared__ float buf[128][2];

    const int gy = blockIdx.y;
    ExpDesc d = (gy >= d3.gy_begin) ? d3 : (gy >= d2.gy_begin) ? d2
              : (gy >= d1.gy_begin) ? d1 : d0;

    const int tid = threadIdx.x;
    const int w = tid >> 6;
    const int l = tid & 63;
    const int mt = blockIdx.x;
    const int wm = (w >> 1) * 64;
    const int wn = (w & 1) * 64;
    const int lane16 = l & 15;
    const int quad = l >> 4;

    const int tiles_begin = (gy - d.gy_begin) * d.slab;
    const int T = d.slab << d.ksl;
    const int kmask = d.kmask;
    const int ksl = d.ksl;

    const size_t tstride = (size_t)128 * d.Kpad;
    const unsigned char* Abase = d.A + (size_t)mt * tstride;
    const unsigned char* Bbase = d.W + (size_t)tiles_begin * tstride;

    const int so0 = tid * 16;
    const int so1 = 4096 + tid * 16;

    // prologue: iter 0 -> slot 0
    load_lds16(Abase + so0, (char*)As[0] + so0);
    load_lds16(Abase + so1, (char*)As[0] + so1);
    load_lds16(Bbase + so0, (char*)Bs[0] + so0);
    load_lds16(Bbase + so1, (char*)Bs[0] + so1);

    float biasc[4], biasn[4];
#pragma unroll
    for (int ni = 0; ni < 4; ++ni)
        biasc[ni] = d.bias[tiles_begin * 128 + wn + ni * 16 + lane16];
#pragma unroll
    for (int ni = 0; ni < 4; ++ni) biasn[ni] = 0.f;

    f32x4 acc[4][4] = {};
    float rowsum[4][4] = {};
    const float c1 = LOG2E / 64.0f;   // undo fp8 scales (4*16) and convert e->2^

    for (int it = 0; it < T; ++it) {
        const int slot = it & 1;
        __syncthreads();

        if (it + 1 < T) {
            const int ns = slot ^ 1;
            const int kc = (it + 1) & kmask;
            if (kmask) {
                const unsigned char* ac = Abase + kc * 8192;
                load_lds16(ac + so0, (char*)As[ns] + so0);
                load_lds16(ac + so1, (char*)As[ns] + so1);
            }
            const unsigned char* bc = Bbase + (size_t)((it + 1) >> ksl) * tstride + kc * 8192;
            load_lds16(bc + so0, (char*)Bs[ns] + so0);
            load_lds16(bc + so1, (char*)Bs[ns] + so1);
            if (kc == 0) {
#pragma unroll
                for (int ni = 0; ni < 4; ++ni)
                    biasn[ni] = d.bias[(tiles_begin + ((it + 1) >> ksl)) * 128 + wn + ni * 16 + lane16];
            }
        }

        const u64* Ar = As[kmask ? slot : 0];
        const u64* Br = Bs[slot];
#pragma unroll
        for (int ks = 0; ks < 2; ++ks) {
            u64 af[4], bfr[4];
#pragma unroll
            for (int mi = 0; mi < 4; ++mi)
                af[mi] = Ar[(ks * 4 + quad) * 128 + wm + mi * 16 + lane16];
#pragma unroll
            for (int ni = 0; ni < 4; ++ni)
                bfr[ni] = Br[(ks * 4 + quad) * 128 + wn + ni * 16 + lane16];
#pragma unroll
            for (int mi = 0; mi < 4; ++mi)
#pragma unroll
                for (int ni = 0; ni < 4; ++ni)
                    acc[mi][ni] = __builtin_amdgcn_mfma_f32_16x16x32_fp8_fp8(
                        (long)af[mi], (long)bfr[ni], acc[mi][ni], 0, 0, 0);
        }

        if ((it & kmask) == kmask) {
#pragma unroll
            for (int mi = 0; mi < 4; ++mi)
#pragma unroll
                for (int r = 0; r < 4; ++r) {
                    float s = exp2f(fmaf(acc[mi][0][r], c1, biasc[0]))
                            + exp2f(fmaf(acc[mi][1][r], c1, biasc[1]))
                            + exp2f(fmaf(acc[mi][2][r], c1, biasc[2]))
                            + exp2f(fmaf(acc[mi][3][r], c1, biasc[3]));
                    rowsum[mi][r] += s;
                }
#pragma unroll
            for (int mi = 0; mi < 4; ++mi)
#pragma unroll
                for (int ni = 0; ni < 4; ++ni)
                    acc[mi][ni] = (f32x4){0.f, 0.f, 0.f, 0.f};
#pragma unroll
            for (int ni = 0; ni < 4; ++ni) biasc[ni] = biasn[ni];
        }
    }

#pragma unroll
    for (int off = 1; off < 16; off <<= 1)
#pragma unroll
        for (int mi = 0; mi < 4; ++mi)
#pragma unroll
            for (int r = 0; r < 4; ++r)
                rowsum[mi][r] += __shfl_xor(rowsum[mi][r], off, 64);

    __syncthreads();
    if (lane16 == 0) {
#pragma unroll
        for (int mi = 0; mi < 4; ++mi)
#pragma unroll
            for (int r = 0; r < 4; ++r)
                buf[wm + mi * 16 + quad * 4 + r][wn >> 6] = rowsum[mi][r];
    }
    __syncthreads();
    if (tid < 128)
        d.part[(size_t)(gy - d.gy_begin) * 1024 + mt * 128 + tid] = buf[tid][0] + buf[tid][1];
}

// ---------------- fused partial-reduce + target-logit extraction ----------------
__global__ void redext(const float* __restrict__ p0, const float* __restrict__ p1,
                       const float* __restrict__ p2, const float* __restrict__ p3,
                       float* __restrict__ S,
                       const unsigned short* __restrict__ Y0, const unsigned short* __restrict__ Y1,
                       const unsigned short* __restrict__ Y2, const unsigned short* __restrict__ Y3,
                       const int* __restrict__ target,
                       const float* __restrict__ W0, const float* __restrict__ b0,
                       const float* __restrict__ W1, const float* __restrict__ b1,
                       const float* __restrict__ W2, const float* __restrict__ b2,
                       const float* __restrict__ W3, const float* __restrict__ b3,
                       const float* __restrict__ cw, const float* __restrict__ cb,
                       float* __restrict__ headlogit, float* __restrict__ taillogit)
{
    if (blockIdx.x < 16) {
        const int idx = blockIdx.x * 256 + threadIdx.x;   // [0,4096)
        const int c = idx >> 10, m = idx & 1023;
        const float* p = (c == 0) ? p0 : (c == 1) ? p1 : (c == 2) ? p2 : p3;
        const int G = (c == 0) ? 157 : (c == 1) ? 40 : (c == 2) ? 79 : 34;
        float s = 0.f;
        for (int y = 0; y < G; ++y) s += p[(size_t)y * 1024 + m];
        S[idx] = s;
        return;
    }
    const int token = (blockIdx.x - 16) * 4 + (threadIdx.x >> 6);
    const int lane = threadIdx.x & 63;
    const int tgt = target[token];
    const int ci = (tgt < 20000) ? 0 : (tgt < 40000) ? 1 : (tgt < 200000) ? 2 : 3;

    {
        const int h = (ci == 0) ? tgt : (20000 + ci - 1);
        const float* row;
        float bb;
        if (h < 20000) { row = W0 + (size_t)h * 1024; bb = b0[h]; }
        else           { row = cw + (size_t)(h - 20000) * 1024; bb = cb[h - 20000]; }
        const unsigned short* y = Y0 + (size_t)token * 1024;
        float s = 0.f;
        for (int k = lane; k < 1024; k += 64) s += bf2f(y[k]) * row[k];
#pragma unroll
        for (int off = 1; off < 64; off <<= 1) s += __shfl_xor(s, off, 64);
        if (lane == 0) headlogit[token] = s + bb;
    }

    float tl = 0.f;
    if (ci > 0) {
        const unsigned short* Y; const float* W; const float* b; int K, ldy, lidx;
        if (ci == 1)      { Y = Y1; W = W1; b = b1; K = 256; ldy = 256; lidx = 20000; }
        else if (ci == 2) { Y = Y2; W = W2; b = b2; K = 64;  ldy = 64;  lidx = 40000; }
        else              { Y = Y3; W = W3; b = b3; K = 16;  ldy = 64;  lidx = 200000; }
        const int r = tgt - lidx;
        const unsigned short* y = Y + (size_t)token * ldy;
        const float* row = W + (size_t)r * K;
        float s = 0.f;
        for (int k = lane; k < K; k += 64) s += bf2f(y[k]) * row[k];
#pragma unroll
        for (int off = 1; off < 64; off <<= 1) s += __shfl_xor(s, off, 64);
        tl = s + b[r];
    }
    if (lane == 0) taillogit[token] = tl;
}

__global__ void finalize_kernel(const float* __restrict__ S,
                                const int* __restrict__ target,
                                const float* __restrict__ headlogit,
                                const float* __restrict__ taillogit,
                                float* __restrict__ out)
{
    __shared__ float red[256];
    const int tid = threadIdx.x;
    float acc = 0.f;
    for (int token = tid; token < 1024; token += 256) {
        const int tgt = target[token];
        const int ci = (tgt < 20000) ? 0 : (tgt < 40000) ? 1 : (tgt < 200000) ? 2 : 3;
        float lp = headlogit[token] - logf(S[token]);
        if (ci > 0)
            lp += taillogit[token] - logf(S[ci * 1024 + token]);
        acc -= lp;
    }
    red[tid] = acc;
    __syncthreads();
    for (int s = 128; s > 0; s >>= 1) {
        if (tid < s) red[tid] += red[tid + s];
        __syncthreads();
    }
    if (tid == 0) out[0] = red[0] * (1.0f / 1024.0f);
}

extern "C" void kernel_launch(void* const* d_in, const int* in_sizes, int n_in,
                              void* d_out, int out_size, void* d_ws, size_t ws_size,
                              hipStream_t stream)
{
    const float* hidden = (const float*)d_in[0];
    const int*   target = (const int*)d_in[1];
    const float* W0 = (const float*)d_in[2];  const float* b0 = (const float*)d_in[3];  const float* P0 = (const float*)d_in[4];
    const float* W1 = (const float*)d_in[5];  const float* b1 = (const float*)d_in[6];  const float* P1 = (const float*)d_in[7];
    const float* W2 = (const float*)d_in[8];  const float* b2 = (const float*)d_in[9];  const float* P2 = (const float*)d_in[10];
    const float* W3 = (const float*)d_in[11]; const float* b3 = (const float*)d_in[12]; const float* P3 = (const float*)d_in[13];
    const float* cw = (const float*)d_in[14]; const float* cb = (const float*)d_in[15];
    float* out = (float*)d_out;

    // ---- workspace layout (byte offsets) ----
    unsigned char* ws = (unsigned char*)d_ws;
    unsigned short* h_bf = (unsigned short*)ws;                       //  2,097,152 B (overlaid later)
    unsigned short* Y0bf = (unsigned short*)(ws + 2097152);           //  2,097,152
    unsigned short* Y1bf = (unsigned short*)(ws + 4194304);           //    524,288
    unsigned short* Y2bf = (unsigned short*)(ws + 4718592);           //    131,072
    unsigned short* Y3bf = (unsigned short*)(ws + 4849664);           //    131,072
    unsigned char* Y0f8 = ws + 4980736;                               //  1,048,576
    unsigned char* Y1f8 = ws + 6029312;                               //    262,144
    unsigned char* Y2f8 = ws + 6291456;                               //     65,536
    unsigned char* Y3f8 = ws + 6356992;                               //     65,536
    unsigned char* Wb0 = ws + 6422528;                                // 20,578,304 (157 tiles)
    unsigned char* Wb1 = ws + 27000832;                               //  5,242,880 (160 tiles)
    unsigned char* Wb2 = ws + 32243712;                               // 10,354,688 (1264 tiles)
    unsigned char* Wb3 = ws + 42598400;                               //  4,456,448 (544 tiles)
    float* bp = (float*)(ws + 47054848);                              //  1,088,000 (272000 f)

    // overlays on h_bf (dead after prepproj)
    float* part0 = (float*)ws;                     // 157*4 KB
    float* part1 = part0 + (size_t)157 * 1024;     //  40*4 KB
    float* part2 = part1 + (size_t)40 * 1024;      //  79*4 KB
    float* part3 = part2 + (size_t)79 * 1024;      //  34*4 KB
    float* S = part3 + (size_t)34 * 1024;          // 4*1024
    float* headlogit = S + 4096;
    float* taillogit = headlogit + 1024;

    cvt_h<<<1024, 256, 0, stream>>>(hidden, h_bf);

    ProjDesc pr0 = { P0, Y0bf, Y0f8, 1024, 1024, 1024, 1024, 0 };
    ProjDesc pr1 = { P1, Y1bf, Y1f8, 256,  256,  256,  256,  8 };
    ProjDesc pr2 = { P2, Y2bf, Y2f8, 64,   64,   64,   64,   10 };
    ProjDesc pr3 = { P3, Y3bf, Y3f8, 64,   16,   16,   64,   11 };
    prepproj<<<2048, 256, 0, stream>>>(h_bf, pr0, pr1, pr2, pr3,
                                       W0, cw, W1, W2, W3,
                                       b0, cb, b1, b2, b3,
                                       Wb0, Wb1, Wb2, Wb3, bp);

    ExpDesc d0 = { Y0f8, Wb0, bp,          part0, 1024, 4, 15, 0,   1 };
    ExpDesc d1 = { Y1f8, Wb1, bp + 20096,  part1, 256,  2, 3,  157, 4 };
    ExpDesc d2 = { Y2f8, Wb2, bp + 40576,  part2, 64,   0, 0,  197, 16 };
    ExpDesc d3 = { Y3f8, Wb3, bp + 202368, part3, 64,   0, 0,  276, 16 };
    exp_gemm<<<dim3(8, 310), 256, 0, stream>>>(d0, d1, d2, d3);

    redext<<<272, 256, 0, stream>>>(part0, part1, part2, part3, S,
                                    Y0bf, Y1bf, Y2bf, Y3bf, target,
                                    W0, b0, W1, b1, W2, b2, W3, b3,
                                    cw, cb, headlogit, taillogit);

    finalize_kernel<<<1, 256, 0, stream>>>(S, target, headlogit, taillogit, out);
}